// Round 14
// baseline (1877.341 us; speedup 1.0000x reference)
//
#include <hip/hip_runtime.h>

#define CDIV(a,b) (((a)+(b)-1)/(b))

typedef __bf16 bf16x8 __attribute__((ext_vector_type(8)));
typedef float  f32x4  __attribute__((ext_vector_type(4)));
#define MFMA16(a,b,c) __builtin_amdgcn_mfma_f32_16x16x32_bf16(a,b,c,0,0,0)

// async 16B global->LDS copy: per-lane global addr, wave-uniform LDS base
__device__ __forceinline__ void ldst16(const unsigned short* g, unsigned short* l){
  __builtin_amdgcn_global_load_lds(
      (const __attribute__((address_space(1))) unsigned int*)g,
      (__attribute__((address_space(3))) unsigned int*)l, 16, 0, 0);
}

// ---------------- wave/block reductions ----------------
__device__ __forceinline__ float waveSum(float v){
#pragma unroll
  for(int o=32;o;o>>=1) v += __shfl_xor(v,o);
  return v;
}
__device__ __forceinline__ float waveMax(float v){
#pragma unroll
  for(int o=32;o;o>>=1) v = fmaxf(v,__shfl_xor(v,o));
  return v;
}

// ---------------- bf16 split helpers ----------------
__device__ __forceinline__ unsigned short f2bf(float f){
  unsigned u = __float_as_uint(f);
  u += 0x7FFFu + ((u>>16)&1u);
  return (unsigned short)(u>>16);
}
__device__ __forceinline__ float bf2f(unsigned short h){
  return __uint_as_float(((unsigned)h)<<16);
}
__device__ __forceinline__ void pack8(const float4& x, const float4& y,
                                      uint4& hi, uint4& lo){
  float v[8] = {x.x,x.y,x.z,x.w,y.x,y.y,y.z,y.w};
  unsigned short h[8], l[8];
#pragma unroll
  for(int i=0;i<8;i++){
    h[i] = f2bf(v[i]);
    l[i] = f2bf(v[i] - bf2f(h[i]));
  }
  hi = make_uint4((unsigned)h[0]|((unsigned)h[1]<<16), (unsigned)h[2]|((unsigned)h[3]<<16),
                  (unsigned)h[4]|((unsigned)h[5]<<16), (unsigned)h[6]|((unsigned)h[7]<<16));
  lo = make_uint4((unsigned)l[0]|((unsigned)l[1]<<16), (unsigned)l[2]|((unsigned)l[3]<<16),
                  (unsigned)l[4]|((unsigned)l[5]<<16), (unsigned)l[6]|((unsigned)l[7]<<16));
}

__device__ __forceinline__ bf16x8 ldsfrag(const unsigned short* base, int row, int kb){
  int off = (row<<7) + (kb<<1);
  off ^= (row&7)<<4;
  return *reinterpret_cast<const bf16x8*>(reinterpret_cast<const char*>(base) + off);
}

// ---------------- MFMA bf16x3 NT GEMM, f32 W (setup paths) ----------------
template<int ACT>
__global__ __launch_bounds__(256)
void gemm3(const float* __restrict__ A, int lda,
           const float* __restrict__ W, int ldw,
           float* __restrict__ C, int ldc,
           const float* __restrict__ bias, int M, int N, int K, float scale)
{
  __shared__ unsigned short AsH[64*64];
  __shared__ unsigned short AsL[64*64];
  __shared__ unsigned short WsH[64*64];
  __shared__ unsigned short WsL[64*64];
  const int tid  = threadIdx.x;
  const int bm   = blockIdx.x*64, bn = blockIdx.y*64;
  const int lane = tid & 63, wid = tid >> 6;
  const int wm   = (wid&1)*32, wn = (wid>>1)*32;
  const int r0   = tid>>3;
  const int kq   = (tid&7)*8;

  float4 gA[2][2], gW[2][2];
  auto loadG = [&](int k0){
#pragma unroll
    for(int i=0;i<2;i++){
      int r = r0 + i*32;
      if(bm+r < M){
        const float* pa = A + (size_t)(bm+r)*lda + k0 + kq;
        gA[i][0] = *reinterpret_cast<const float4*>(pa);
        gA[i][1] = *reinterpret_cast<const float4*>(pa+4);
      } else {
        gA[i][0] = make_float4(0.f,0.f,0.f,0.f);
        gA[i][1] = make_float4(0.f,0.f,0.f,0.f);
      }
      const float* pw = W + (size_t)(bn+r)*ldw + k0 + kq;
      gW[i][0] = *reinterpret_cast<const float4*>(pw);
      gW[i][1] = *reinterpret_cast<const float4*>(pw+4);
    }
  };
  auto writeL = [&](){
#pragma unroll
    for(int i=0;i<2;i++){
      int r = r0 + i*32;
      int off = (r<<7) + (tid&7)*16;
      off ^= (r&7)<<4;
      uint4 hi, lo;
      pack8(gA[i][0], gA[i][1], hi, lo);
      *reinterpret_cast<uint4*>(reinterpret_cast<char*>(AsH) + off) = hi;
      *reinterpret_cast<uint4*>(reinterpret_cast<char*>(AsL) + off) = lo;
      pack8(gW[i][0], gW[i][1], hi, lo);
      *reinterpret_cast<uint4*>(reinterpret_cast<char*>(WsH) + off) = hi;
      *reinterpret_cast<uint4*>(reinterpret_cast<char*>(WsL) + off) = lo;
    }
  };

  f32x4 acc[2][2];
#pragma unroll
  for(int mi=0;mi<2;mi++)
#pragma unroll
    for(int ni=0;ni<2;ni++) acc[mi][ni] = f32x4{0.f,0.f,0.f,0.f};

  loadG(0);
  for(int k0=0; k0<K; k0+=64){
    __syncthreads();
    writeL();
    __syncthreads();
    if(k0+64 < K) loadG(k0+64);
    const int lk = (lane>>4)*8;
    const int lc = lane&15;
#pragma unroll
    for(int kk=0; kk<2; kk++){
      int kb = kk*32 + lk;
      bf16x8 aH[2], aL[2], bH[2], bL[2];
#pragma unroll
      for(int m=0;m<2;m++){
        aH[m] = ldsfrag(AsH, wm + lc + m*16, kb);
        aL[m] = ldsfrag(AsL, wm + lc + m*16, kb);
        bH[m] = ldsfrag(WsH, wn + lc + m*16, kb);
        bL[m] = ldsfrag(WsL, wn + lc + m*16, kb);
      }
#pragma unroll
      for(int mi=0;mi<2;mi++)
#pragma unroll
        for(int ni=0;ni<2;ni++){
          acc[mi][ni] = MFMA16(aH[mi], bH[ni], acc[mi][ni]);
          acc[mi][ni] = MFMA16(aH[mi], bL[ni], acc[mi][ni]);
          acc[mi][ni] = MFMA16(aL[mi], bH[ni], acc[mi][ni]);
        }
    }
  }

  const int lr = lane>>4, lc = lane&15;
#pragma unroll
  for(int mi=0;mi<2;mi++)
#pragma unroll
    for(int ni=0;ni<2;ni++)
#pragma unroll
      for(int r=0;r<4;r++){
        int row = bm + wm + mi*16 + lr*4 + r;
        if(row>=M) continue;
        int col = bn + wn + ni*16 + lc;
        float v = acc[mi][ni][r]*scale + (bias ? bias[col] : 0.f);
        if(ACT==1) v = 0.5f*v*(1.f+erff(v*0.70710678118654752f));
        C[(size_t)row*ldc+col] = v;
      }
}

// ---------------- batched-z MFMA bf16x3 NT GEMM (attention scores) ----------------
__global__ __launch_bounds__(256)
void gemm3z(const float* A0, int lda, int sAz,
            const float* W0, int ldw, int sWz,
            float* C0, int ldc, int sCz,
            int M, int N, int K, float scale)
{
  const float* A = A0 + (size_t)blockIdx.z*sAz;
  const float* W = W0 + (size_t)blockIdx.z*sWz;
  float*       C = C0 + (size_t)blockIdx.z*sCz;
  __shared__ unsigned short AsH[64*64];
  __shared__ unsigned short AsL[64*64];
  __shared__ unsigned short WsH[64*64];
  __shared__ unsigned short WsL[64*64];
  const int tid  = threadIdx.x;
  const int bm   = blockIdx.x*64, bn = blockIdx.y*64;
  const int lane = tid & 63, wid = tid >> 6;
  const int wm   = (wid&1)*32, wn = (wid>>1)*32;
  const int r0   = tid>>3;
  const int kq   = (tid&7)*8;

  float4 gA[2][2], gW[2][2];
  auto loadG = [&](int k0){
#pragma unroll
    for(int i=0;i<2;i++){
      int r = r0 + i*32;
      if(bm+r < M){
        const float* pa = A + (size_t)(bm+r)*lda + k0 + kq;
        gA[i][0] = *reinterpret_cast<const float4*>(pa);
        gA[i][1] = *reinterpret_cast<const float4*>(pa+4);
      } else {
        gA[i][0] = make_float4(0.f,0.f,0.f,0.f);
        gA[i][1] = make_float4(0.f,0.f,0.f,0.f);
      }
      const float* pw = W + (size_t)(bn+r)*ldw + k0 + kq;
      gW[i][0] = *reinterpret_cast<const float4*>(pw);
      gW[i][1] = *reinterpret_cast<const float4*>(pw+4);
    }
  };
  auto writeL = [&](){
#pragma unroll
    for(int i=0;i<2;i++){
      int r = r0 + i*32;
      int off = (r<<7) + (tid&7)*16;
      off ^= (r&7)<<4;
      uint4 hi, lo;
      pack8(gA[i][0], gA[i][1], hi, lo);
      *reinterpret_cast<uint4*>(reinterpret_cast<char*>(AsH) + off) = hi;
      *reinterpret_cast<uint4*>(reinterpret_cast<char*>(AsL) + off) = lo;
      pack8(gW[i][0], gW[i][1], hi, lo);
      *reinterpret_cast<uint4*>(reinterpret_cast<char*>(WsH) + off) = hi;
      *reinterpret_cast<uint4*>(reinterpret_cast<char*>(WsL) + off) = lo;
    }
  };

  f32x4 acc[2][2];
#pragma unroll
  for(int mi=0;mi<2;mi++)
#pragma unroll
    for(int ni=0;ni<2;ni++) acc[mi][ni] = f32x4{0.f,0.f,0.f,0.f};

  loadG(0);
  for(int k0=0; k0<K; k0+=64){
    __syncthreads();
    writeL();
    __syncthreads();
    if(k0+64 < K) loadG(k0+64);
    const int lk = (lane>>4)*8;
    const int lc = lane&15;
#pragma unroll
    for(int kk=0; kk<2; kk++){
      int kb = kk*32 + lk;
      bf16x8 aH[2], aL[2], bH[2], bL[2];
#pragma unroll
      for(int m=0;m<2;m++){
        aH[m] = ldsfrag(AsH, wm + lc + m*16, kb);
        aL[m] = ldsfrag(AsL, wm + lc + m*16, kb);
        bH[m] = ldsfrag(WsH, wn + lc + m*16, kb);
        bL[m] = ldsfrag(WsL, wn + lc + m*16, kb);
      }
#pragma unroll
      for(int mi=0;mi<2;mi++)
#pragma unroll
        for(int ni=0;ni<2;ni++){
          acc[mi][ni] = MFMA16(aH[mi], bH[ni], acc[mi][ni]);
          acc[mi][ni] = MFMA16(aH[mi], bL[ni], acc[mi][ni]);
          acc[mi][ni] = MFMA16(aL[mi], bH[ni], acc[mi][ni]);
        }
    }
  }

  const int lr = lane>>4, lc = lane&15;
#pragma unroll
  for(int mi=0;mi<2;mi++)
#pragma unroll
    for(int ni=0;ni<2;ni++)
#pragma unroll
      for(int r=0;r<4;r++){
        int row = bm + wm + mi*16 + lr*4 + r;
        if(row>=M) continue;
        int col = bn + wn + ni*16 + lc;
        C[(size_t)row*ldc+col] = acc[mi][ni][r]*scale;
      }
}

// ---------------- MFMA bf16x3 NT GEMM, tile-swizzled pre-split W ----------------
template<int ACT>
__global__ __launch_bounds__(256)
void gemm3s(const float* __restrict__ A, int lda,
            const unsigned short* __restrict__ WH,
            const unsigned short* __restrict__ WL, int ldw,
            float* __restrict__ C, int ldc,
            const float* __restrict__ bias, int M, int N, int K)
{
  __shared__ unsigned short AsH[4096];
  __shared__ unsigned short AsL[4096];
  __shared__ unsigned short WsH0[4096], WsL0[4096];
  __shared__ unsigned short WsH1[4096], WsL1[4096];
  const int tid  = threadIdx.x;
  const int bm   = blockIdx.x*64, bn = blockIdx.y*64;
  const int lane = tid & 63, wid = tid >> 6;
  const int wm   = (wid&1)*32, wn = (wid>>1)*32;
  const int r0   = tid>>3;
  const int kq   = (tid&7)*8;
  const int KT   = ldw >> 6;
  const unsigned short* WHt = WH + (size_t)(bn>>6)*KT*4096;
  const unsigned short* WLt = WL + (size_t)(bn>>6)*KT*4096;
  const int wbase = wid*1024;

  float4 gA[2][2];
  auto loadGA = [&](int k0){
#pragma unroll
    for(int i=0;i<2;i++){
      int r = r0 + i*32;
      if(bm+r < M){
        const float* pa = A + (size_t)(bm+r)*lda + k0 + kq;
        gA[i][0] = *reinterpret_cast<const float4*>(pa);
        gA[i][1] = *reinterpret_cast<const float4*>(pa+4);
      } else {
        gA[i][0] = make_float4(0.f,0.f,0.f,0.f);
        gA[i][1] = make_float4(0.f,0.f,0.f,0.f);
      }
    }
  };
  auto writeLA = [&](){
#pragma unroll
    for(int i=0;i<2;i++){
      int r = r0 + i*32;
      int off = (r<<7) + (tid&7)*16;
      off ^= (r&7)<<4;
      uint4 hi, lo;
      pack8(gA[i][0], gA[i][1], hi, lo);
      *reinterpret_cast<uint4*>(reinterpret_cast<char*>(AsH) + off) = hi;
      *reinterpret_cast<uint4*>(reinterpret_cast<char*>(AsL) + off) = lo;
    }
  };
  auto asyncW = [&](int kt, unsigned short* dH, unsigned short* dL){
    const unsigned short* gh = WHt + (size_t)kt*4096 + wbase + lane*8;
    const unsigned short* gl = WLt + (size_t)kt*4096 + wbase + lane*8;
    ldst16(gh,       dH + wbase);
    ldst16(gh + 512, dH + wbase + 512);
    ldst16(gl,       dL + wbase);
    ldst16(gl + 512, dL + wbase + 512);
  };

  f32x4 acc[2][2];
#pragma unroll
  for(int mi=0;mi<2;mi++)
#pragma unroll
    for(int ni=0;ni<2;ni++) acc[mi][ni] = f32x4{0.f,0.f,0.f,0.f};

  auto compute = [&](const unsigned short* Wh, const unsigned short* Wl){
    const int lk = (lane>>4)*8;
    const int lc = lane&15;
#pragma unroll
    for(int kk=0; kk<2; kk++){
      int kb = kk*32 + lk;
      bf16x8 aH[2], aL[2], bH[2], bL[2];
#pragma unroll
      for(int m=0;m<2;m++){
        aH[m] = ldsfrag(AsH, wm + lc + m*16, kb);
        aL[m] = ldsfrag(AsL, wm + lc + m*16, kb);
        bH[m] = ldsfrag(Wh, wn + lc + m*16, kb);
        bL[m] = ldsfrag(Wl, wn + lc + m*16, kb);
      }
#pragma unroll
      for(int mi=0;mi<2;mi++)
#pragma unroll
        for(int ni=0;ni<2;ni++){
          acc[mi][ni] = MFMA16(aH[mi], bH[ni], acc[mi][ni]);
          acc[mi][ni] = MFMA16(aH[mi], bL[ni], acc[mi][ni]);
          acc[mi][ni] = MFMA16(aL[mi], bH[ni], acc[mi][ni]);
        }
    }
  };

  asyncW(0, WsH0, WsL0);
  loadGA(0);
  int k0 = 0, kt = 0;
  while(true){
    __syncthreads();
    writeLA();
    __syncthreads();
    if(k0+64 < K){ asyncW(kt+1, WsH1, WsL1); loadGA(k0+64); }
    compute(WsH0, WsL0);
    k0 += 64; kt++;
    if(k0 >= K) break;
    __syncthreads();
    writeLA();
    __syncthreads();
    if(k0+64 < K){ asyncW(kt+1, WsH0, WsL0); loadGA(k0+64); }
    compute(WsH1, WsL1);
    k0 += 64; kt++;
    if(k0 >= K) break;
  }

  const int lr = lane>>4, lc = lane&15;
#pragma unroll
  for(int mi=0;mi<2;mi++)
#pragma unroll
    for(int ni=0;ni<2;ni++)
#pragma unroll
      for(int r=0;r<4;r++){
        int row = bm + wm + mi*16 + lr*4 + r;
        if(row>=M) continue;
        int col = bn + wn + ni*16 + lc;
        float v = acc[mi][ni][r] + (bias ? bias[col] : 0.f);
        if(ACT==1) v = 0.5f*v*(1.f+erff(v*0.70710678118654752f));
        C[(size_t)row*ldc+col] = v;
      }
}

// ---------------- split-K batched MFMA GEMM, tile-swizzled pre-split W -----------
__global__ __launch_bounds__(256)
void gemm3bk(const float* __restrict__ A0, int lda, int sAz,
             const unsigned short* __restrict__ WH0,
             const unsigned short* __restrict__ WL0, int ldw, int sWz,
             float* __restrict__ Cp, int M, int N, int KLEN, int KS)
{
  __shared__ unsigned short AsH[4096];
  __shared__ unsigned short AsL[4096];
  __shared__ unsigned short WsH0[4096], WsL0[4096];
  __shared__ unsigned short WsH1[4096], WsL1[4096];
  const int z  = blockIdx.z;
  const int bz = z / KS, ks = z - bz*KS;
  const float* A = A0 + (size_t)bz*sAz;
  const unsigned short* WH = WH0 + (size_t)bz*sWz;
  const unsigned short* WL = WL0 + (size_t)bz*sWz;
  const int kbeg = ks*KLEN, kend = kbeg + KLEN;
  const int tid  = threadIdx.x;
  const int bm   = blockIdx.x*64, bn = blockIdx.y*64;
  const int lane = tid & 63, wid = tid >> 6;
  const int wm   = (wid&1)*32, wn = (wid>>1)*32;
  const int r0   = tid>>3;
  const int kq   = (tid&7)*8;
  const int KT   = ldw >> 6;
  const unsigned short* WHt = WH + (size_t)(bn>>6)*KT*4096;
  const unsigned short* WLt = WL + (size_t)(bn>>6)*KT*4096;
  const int wbase = wid*1024;

  float4 gA[2][2];
  auto loadGA = [&](int k0){
#pragma unroll
    for(int i=0;i<2;i++){
      int r = r0 + i*32;
      if(bm+r < M){
        const float* pa = A + (size_t)(bm+r)*lda + k0 + kq;
        gA[i][0] = *reinterpret_cast<const float4*>(pa);
        gA[i][1] = *reinterpret_cast<const float4*>(pa+4);
      } else {
        gA[i][0] = make_float4(0.f,0.f,0.f,0.f);
        gA[i][1] = make_float4(0.f,0.f,0.f,0.f);
      }
    }
  };
  auto writeLA = [&](){
#pragma unroll
    for(int i=0;i<2;i++){
      int r = r0 + i*32;
      int off = (r<<7) + (tid&7)*16;
      off ^= (r&7)<<4;
      uint4 hi, lo;
      pack8(gA[i][0], gA[i][1], hi, lo);
      *reinterpret_cast<uint4*>(reinterpret_cast<char*>(AsH) + off) = hi;
      *reinterpret_cast<uint4*>(reinterpret_cast<char*>(AsL) + off) = lo;
    }
  };
  auto asyncW = [&](int kt, unsigned short* dH, unsigned short* dL){
    const unsigned short* gh = WHt + (size_t)kt*4096 + wbase + lane*8;
    const unsigned short* gl = WLt + (size_t)kt*4096 + wbase + lane*8;
    ldst16(gh,       dH + wbase);
    ldst16(gh + 512, dH + wbase + 512);
    ldst16(gl,       dL + wbase);
    ldst16(gl + 512, dL + wbase + 512);
  };

  f32x4 acc[2][2];
#pragma unroll
  for(int mi=0;mi<2;mi++)
#pragma unroll
    for(int ni=0;ni<2;ni++) acc[mi][ni] = f32x4{0.f,0.f,0.f,0.f};

  auto compute = [&](const unsigned short* Wh, const unsigned short* Wl){
    const int lk = (lane>>4)*8;
    const int lc = lane&15;
#pragma unroll
    for(int kk=0; kk<2; kk++){
      int kb = kk*32 + lk;
      bf16x8 aH[2], aL[2], bH[2], bL[2];
#pragma unroll
      for(int m=0;m<2;m++){
        aH[m] = ldsfrag(AsH, wm + lc + m*16, kb);
        aL[m] = ldsfrag(AsL, wm + lc + m*16, kb);
        bH[m] = ldsfrag(Wh, wn + lc + m*16, kb);
        bL[m] = ldsfrag(Wl, wn + lc + m*16, kb);
      }
#pragma unroll
      for(int mi=0;mi<2;mi++)
#pragma unroll
        for(int ni=0;ni<2;ni++){
          acc[mi][ni] = MFMA16(aH[mi], bH[ni], acc[mi][ni]);
          acc[mi][ni] = MFMA16(aH[mi], bL[ni], acc[mi][ni]);
          acc[mi][ni] = MFMA16(aL[mi], bH[ni], acc[mi][ni]);
        }
    }
  };

  asyncW(kbeg>>6, WsH0, WsL0);
  loadGA(kbeg);
  int k0 = kbeg, kt = kbeg>>6;
  while(true){
    __syncthreads();
    writeLA();
    __syncthreads();
    if(k0+64 < kend){ asyncW(kt+1, WsH1, WsL1); loadGA(k0+64); }
    compute(WsH0, WsL0);
    k0 += 64; kt++;
    if(k0 >= kend) break;
    __syncthreads();
    writeLA();
    __syncthreads();
    if(k0+64 < kend){ asyncW(kt+1, WsH0, WsL0); loadGA(k0+64); }
    compute(WsH1, WsL1);
    k0 += 64; kt++;
    if(k0 >= kend) break;
  }

  float* Cpz = Cp + (size_t)z*M*N;
  const int lr = lane>>4, lc = lane&15;
#pragma unroll
  for(int mi=0;mi<2;mi++)
#pragma unroll
    for(int ni=0;ni<2;ni++)
#pragma unroll
      for(int r=0;r<4;r++){
        int row = bm + wm + mi*16 + lr*4 + r;
        if(row>=M) continue;
        int col = bn + wn + ni*16 + lc;
        Cpz[(size_t)row*N+col] = acc[mi][ni][r];
      }
}

// out[b*sCz + m*ldc + n] = act(scale * sum_ks Cp[(b*KS+ks)*MN + e] + bias[n])
template<int ACT>
__global__ __launch_bounds__(256)
void reduce_k(const float* __restrict__ Cp, float* __restrict__ C,
              const float* __restrict__ bias, int MN, int N, int ldc,
              int sCz, int KS, int NB, float scale)
{
  int gid = blockIdx.x*256+threadIdx.x;
  if(gid >= NB*MN) return;
  int b = gid / MN, e = gid - b*MN;
  int m = e / N, n = e - m*N;
  const float* p = Cp + (size_t)b*KS*MN + e;
  float s = 0.f;
  for(int k=0;k<KS;k++) s += p[(size_t)k*MN];
  s = s*scale + (bias ? bias[n] : 0.f);
  if(ACT==1) s = 0.5f*s*(1.f+erff(s*0.70710678118654752f));
  C[(size_t)b*sCz + (size_t)m*ldc + n] = s;
}

// fused split-K reduce + bias + residual + LayerNorm (N=384), block per row
__global__ __launch_bounds__(128)
void reduce_ln(const float* __restrict__ Pp, const float* __restrict__ X,
               float* __restrict__ O, const float* __restrict__ g,
               const float* __restrict__ be, const float* __restrict__ bias,
               int M, int KS)
{
  int row = blockIdx.x;
  if(row>=M) return;
  int tid = threadIdx.x;
  const float* x = X + (size_t)row*384;
  float* o = O + (size_t)row*384;
  float v[3]; float s=0.f;
#pragma unroll
  for(int i=0;i<3;i++){
    int c = tid + i*128;
    float t = bias ? bias[c] : 0.f;
    const float* p = Pp + (size_t)row*384 + c;
    for(int k=0;k<KS;k++) t += p[(size_t)k*M*384];
    v[i] = x[c] + t; s += v[i];
  }
  s = waveSum(s);
  __shared__ float p1[2];
  if((tid&63)==0) p1[tid>>6]=s;
  __syncthreads();
  float mean = (p1[0]+p1[1])*(1.f/384.f);
  float vs=0.f;
#pragma unroll
  for(int i=0;i<3;i++){ float d=v[i]-mean; vs += d*d; }
  vs = waveSum(vs);
  __shared__ float p2[2];
  if((tid&63)==0) p2[tid>>6]=vs;
  __syncthreads();
  float rstd = rsqrtf((p2[0]+p2[1])*(1.f/384.f) + 1e-5f);
#pragma unroll
  for(int i=0;i<3;i++){ int c = tid + i*128; o[c] = (v[i]-mean)*rstd*g[c] + be[c]; }
}

// ---------------- f32 NN GEMM (setup compositions) ----------------
__global__ __launch_bounds__(256)
void gemm_nn(const float* __restrict__ A, int lda,
             const float* __restrict__ Bm, int ldb,
             float* __restrict__ C, int ldc,
             int M, int N, int K, float scale)
{
  __shared__ float As[16][68];
  __shared__ float Bs[16][68];
  const int bm = blockIdx.x*64, bn = blockIdx.y*64;
  const int tid = threadIdx.x;
  const int lr = tid>>2;
  const int kq = (tid&3)<<2;
  const int kr = tid>>4;
  const int nq = (tid&15)<<2;
  const int tx = tid&15, ty = tid>>4;
  float acc[4][4] = {};
  for(int k0=0;k0<K;k0+=16){
    float4 av = make_float4(0.f,0.f,0.f,0.f), bv = make_float4(0.f,0.f,0.f,0.f);
    if(bm+lr < M && k0+kq < K) av = *reinterpret_cast<const float4*>(A + (size_t)(bm+lr)*lda + k0+kq);
    if(k0+kr < K && bn+nq < N) bv = *reinterpret_cast<const float4*>(Bm + (size_t)(k0+kr)*ldb + bn+nq);
    As[kq+0][lr]=av.x; As[kq+1][lr]=av.y; As[kq+2][lr]=av.z; As[kq+3][lr]=av.w;
    Bs[kr][nq+0]=bv.x; Bs[kr][nq+1]=bv.y; Bs[kr][nq+2]=bv.z; Bs[kr][nq+3]=bv.w;
    __syncthreads();
#pragma unroll
    for(int k=0;k<16;k++){
      float4 a4 = *reinterpret_cast<const float4*>(&As[k][ty<<2]);
      float4 b4 = *reinterpret_cast<const float4*>(&Bs[k][tx<<2]);
      float aa[4]={a4.x,a4.y,a4.z,a4.w};
      float bb[4]={b4.x,b4.y,b4.z,b4.w};
#pragma unroll
      for(int i=0;i<4;i++)
#pragma unroll
        for(int j=0;j<4;j++) acc[i][j] = fmaf(aa[i],bb[j],acc[i][j]);
    }
    __syncthreads();
  }
#pragma unroll
  for(int i=0;i<4;i++){
    int row = bm + (ty<<2) + i;
    if(row>=M) continue;
#pragma unroll
    for(int j=0;j<4;j++){
      int col = bn + (tx<<2) + j;
      if(col>=N) continue;
      C[(size_t)row*ldc+col]=acc[i][j]*scale;
    }
  }
}

// ---------------- LayerNorm(x + t), row-per-block; optional hid extract ----------
__global__ __launch_bounds__(128)
void add_ln(const float* __restrict__ X, const float* __restrict__ T,
            float* __restrict__ O, const float* __restrict__ g,
            const float* __restrict__ be, int M, float* __restrict__ hid)
{
  int row = blockIdx.x;
  if(row>=M) return;
  const float* x = X + (size_t)row*384;
  const float* t = T + (size_t)row*384;
  float* o = O + (size_t)row*384;
  int tid = threadIdx.x;
  float v[3]; float s=0.f;
#pragma unroll
  for(int i=0;i<3;i++){ int c = tid + i*128; v[i] = x[c] + t[c]; s += v[i]; }
  s = waveSum(s);
  __shared__ float p1[2];
  if((tid&63)==0) p1[tid>>6]=s;
  __syncthreads();
  float mean = (p1[0]+p1[1])*(1.f/384.f);
  float vs=0.f;
#pragma unroll
  for(int i=0;i<3;i++){ float d=v[i]-mean; vs += d*d; }
  vs = waveSum(vs);
  __shared__ float p2[2];
  if((tid&63)==0) p2[tid>>6]=vs;
  __syncthreads();
  float rstd = rsqrtf((p2[0]+p2[1])*(1.f/384.f) + 1e-5f);
#pragma unroll
  for(int i=0;i<3;i++){
    int c = tid + i*128;
    float r = (v[i]-mean)*rstd*g[c] + be[c];
    o[c] = r;
    if(hid && (row&1)) hid[(size_t)(row>>1)*384 + c] = r;
  }
}

// ---------------- row softmax with ld + zero-pad tail ----------------
__global__ __launch_bounds__(256)
void softmax_rows(float* __restrict__ X, int ld, int cols)
{
  float* x = X + (size_t)blockIdx.x*ld;
  int tid = threadIdx.x;
  float m = -1e30f;
  for(int c=tid;c<cols;c+=256) m = fmaxf(m, x[c]);
  m = waveMax(m);
  __shared__ float sm[4];
  if((tid&63)==0) sm[tid>>6]=m;
  __syncthreads();
  m = fmaxf(fmaxf(sm[0],sm[1]),fmaxf(sm[2],sm[3]));
  float s=0.f;
  for(int c=tid;c<cols;c+=256){ float e = expf(x[c]-m); x[c]=e; s+=e; }
  s = waveSum(s);
  __shared__ float ss[4];
  if((tid&63)==0) ss[tid>>6]=s;
  __syncthreads();
  s = ss[0]+ss[1]+ss[2]+ss[3];
  float inv = 1.f/s;
  for(int c=tid;c<cols;c+=256) x[c]*=inv;
  for(int c=cols+tid;c<ld;c+=256) x[c]=0.f;
}

// ---------------- setup kernels ----------------
__global__ void prep_conv(const float* __restrict__ cw, const float* __restrict__ cb,
                          float* __restrict__ Wc, float* __restrict__ cb768){
  int gid = blockIdx.x*256+threadIdx.x;
  if(gid >= 384*384) return;
  int i = gid % 384, o = gid / 384;
  const float* w = cw + (size_t)gid*3;
  Wc[(size_t)o*768 + i]            = w[1];
  Wc[(size_t)o*768 + 384 + i]      = w[2];
  Wc[(size_t)(384+o)*768 + i]      = w[0];
  Wc[(size_t)(384+o)*768 + 384 + i]= w[1];
  if(gid < 768) cb768[gid] = cb[gid % 384];
}

__global__ void vt_k(const float* __restrict__ qkv, float* __restrict__ VT){
  int gid = blockIdx.x*256+threadIdx.x;
  if(gid >= 2*192*512) return;
  int k = gid & 511; int n = (gid>>9) % 192; int h = gid / 98304;
  VT[gid] = (k<500) ? qkv[(size_t)k*1152 + 768 + h*192 + n] : 0.f;
}

// pad K1 to 512 rows (zeros beyond 500)
__global__ void pad_k1(const float* __restrict__ K1, float* __restrict__ Kp){
  int gid = blockIdx.x*256+threadIdx.x;
  if(gid >= 512*384) return;
  int j = gid / 384;
  Kp[gid] = (j<500) ? K1[gid] : 0.f;
}

__global__ void compose_bias(const float* __restrict__ inw, const float* __restrict__ inb,
                             const float* __restrict__ qb, const float* __restrict__ kb,
                             const float* __restrict__ vb, float* __restrict__ cb){
  int gid = blockIdx.x*256+threadIdx.x;
  if(gid>=1536) return;
  int seg = gid/384, i = gid%384;
  const float* wrow; const float* bsrc; float b2;
  if(seg==0){ wrow=inw + (size_t)i*384;       bsrc=qb; b2=inb[i]; }
  else if(seg==1){ wrow=inw + (size_t)(384+i)*384; bsrc=kb; b2=inb[384+i]; }
  else if(seg==2){ wrow=inw + (size_t)(768+i)*384; bsrc=vb; b2=inb[768+i]; }
  else          { wrow=inw + (size_t)(768+i)*384; bsrc=kb; b2=inb[768+i]; }
  float s=0.f;
  for(int t=0;t<384;t++) s = fmaf(wrow[t], bsrc[t], s);
  cb[gid] = s + b2;
}

#define NSEG 16
struct SplitArgs {
  const float* src[NSEG];
  unsigned short* dh[NSEG];
  unsigned short* dl[NSEG];
  int start[NSEG+1];
  int ld[NSEG];
};
// split f32 -> bf16 hi/lo, writing into tile-blocked LDS-image (XOR-swizzled) layout
__global__ void split_all(SplitArgs a){
  int gid = blockIdx.x*256+threadIdx.x;
  if(gid >= a.start[NSEG]) return;
  int s=0;
  while(s<NSEG-1 && gid >= a.start[s+1]) s++;
  int off = gid - a.start[s];
  int K = a.ld[s];
  int r = off / K, c = off - r*K;
  int dst = ((r>>6)*(K>>6) + (c>>6))*4096 + ((r&63)<<6) + ((c&63) ^ ((r&7)<<3));
  float v = a.src[s][off];
  unsigned short h = f2bf(v);
  a.dh[s][dst] = h;
  a.dl[s][dst] = f2bf(v - bf2f(h));
}

__global__ void seq_init(const int* __restrict__ inp, const float* __restrict__ emb,
                         const float* __restrict__ rp, float* __restrict__ seq){
  int gid = blockIdx.x*256+threadIdx.x;
  if(gid >= 128*8*384) return;
  int j = gid % 384; int l = (gid/384) & 7; int b = gid / 3072;
  int tok = inp[b*8 + l];
  seq[gid] = emb[(size_t)tok*384 + j] + rp[l*384 + j];
}

// ---------------- merge-loop kernels ----------------
__global__ void build_pairs(const float* __restrict__ seq, const float* __restrict__ rp,
                            float* __restrict__ pairs, int N, int P){
  int gid = blockIdx.x*256+threadIdx.x;
  if(gid >= N*768) return;
  int c = gid % 768; int n = gid / 768;
  int t = c / 384; int j = c % 384;
  int i = n % P; int b = n / P;
  pairs[gid] = seq[((size_t)b*8 + i + t)*384 + j] + rp[t*384 + j];
}

// fused len-2 attention: one block per pair (scores + softmax + PV)
__global__ __launch_bounds__(256)
void attn2_one(const float* __restrict__ QKV, float* __restrict__ O, int N){
  int n = blockIdx.x;
  if(n>=N) return;
  int tid = threadIdx.x, lane = tid&63, h = tid>>6;
  __shared__ float pr[4][2][2];
  const float* base = QKV + (size_t)(2*n)*1152;
  const float* q0 = base + h*96;
  const float* q1 = base + 1152 + h*96;
  const float* k0 = base + 384 + h*96;
  const float* k1 = base + 1152 + 384 + h*96;
  float q0a=q0[lane], q1a=q1[lane], k0a=k0[lane], k1a=k1[lane];
  float q0b=0.f,q1b=0.f,k0b=0.f,k1b=0.f;
  if(lane<32){ q0b=q0[64+lane]; q1b=q1[64+lane]; k0b=k0[64+lane]; k1b=k1[64+lane]; }
  float s00 = waveSum(q0a*k0a + q0b*k0b);
  float s01 = waveSum(q0a*k1a + q0b*k1b);
  float s10 = waveSum(q1a*k0a + q1b*k0b);
  float s11 = waveSum(q1a*k1a + q1b*k1b);
  if(lane==0){
    const float sc = 0.1020620726159658f;   // 1/sqrt(96)
    s00*=sc; s01*=sc; s10*=sc; s11*=sc;
    float m0=fmaxf(s00,s01); float e00=expf(s00-m0), e01=expf(s01-m0); float i0=1.f/(e00+e01);
    float m1=fmaxf(s10,s11); float e10=expf(s10-m1), e11=expf(s11-m1); float i1=1.f/(e10+e11);
    pr[h][0][0]=e00*i0; pr[h][0][1]=e01*i0;
    pr[h][1][0]=e10*i1; pr[h][1][1]=e11*i1;
  }
  __syncthreads();
  const float* v0 = base + 768;
  const float* v1 = base + 1152 + 768;
  float* o = O + (size_t)(2*n)*384;
#pragma unroll
  for(int i=0;i<3;i++){
    int c = tid + i*256;
    int t = c / 384, j = c % 384; int hh = j/96;
    o[(size_t)t*384 + j] = pr[hh][t][0]*v0[j] + pr[hh][t][1]*v1[j];
  }
}

// fused optional-scatter + score + argmax + entropy + gather from hid[b][7][384]
__global__ __launch_bounds__(256)
void score_select3(float* __restrict__ hid, const float* __restrict__ xb,
                   const float* __restrict__ w, const float* __restrict__ b0,
                   int P, int* __restrict__ idxb, float* __restrict__ lossSlot,
                   float* __restrict__ sel, int doScatter){
  int b = blockIdx.x;
  int tid = threadIdx.x, lane = tid&63, wv = tid>>6;
  __shared__ float scs[8];
  __shared__ int sidx;
  if(doScatter){
    int oldIdx = idxb[b];
#pragma unroll
    for(int e=0;e<2;e++){
      int s = oldIdx-1+e; s = max(0, min(s, P-1));
      const float* src = xb + ((size_t)(2*(2*b+e)+1))*384;
      float* dst = hid + ((size_t)b*7 + s)*384;
      for(int c=tid;c<384;c+=256) dst[c] = src[c];
      __syncthreads();
    }
  }
  for(int pi=wv; pi<P; pi+=4){
    const float* x = hid + ((size_t)b*7 + pi)*384;
    float s=0.f;
#pragma unroll
    for(int i=0;i<6;i++){ int c = lane + i*64; s = fmaf(x[c], w[c], s); }
    s = waveSum(s);
    if(lane==0) scs[pi] = 1.f/(1.f+expf(-(s + b0[0])));
  }
  __syncthreads();
  if(tid==0){
    float m = scs[0]; int am = 0;
    for(int i=1;i<P;i++){ float v=scs[i]; if(v>m){m=v;am=i;} }
    float z=0.f, sx=0.f;
    for(int i=0;i<P;i++){ float e=expf(scs[i]-m); z+=e; sx=fmaf(e,scs[i],sx); }
    lossSlot[(size_t)b*9] = (m + logf(z)) - sx/z;
    idxb[b] = am;
    sidx = am;
  }
  __syncthreads();
  const float* src = hid + ((size_t)b*7 + sidx)*384;
  for(int c=tid;c<384;c+=256) sel[(size_t)b*384+c] = src[c];
}

// ---------------- fused attention tail: softmax (+NE in-kernel extra keys) + PV ----
// block m = h*R + r; S holds raw scores [h][R][512]; V is f32 [500][384].
template<int NE>
__global__ __launch_bounds__(256)
void attn_tail(const float* __restrict__ S, const float* __restrict__ qkv1,
               const float* __restrict__ V1, float* __restrict__ O, int R){
  int m = blockIdx.x;
  int r = m % R, h = m / R;
  int rbase = (NE==2) ? (r & ~1) : r;
  const float* x = S + (size_t)m*512;
  int tid = threadIdx.x, lane = tid&63, wv = tid>>6;
  __shared__ float pr[500];
  __shared__ float r4[4];
  __shared__ float exs[2];
  __shared__ float red[4][64];
  for(int c=tid;c<500;c+=256) pr[c] = x[c];
  if(wv < NE){
    const float* q = qkv1 + (size_t)r*1152 + h*64;
    const float* k = qkv1 + (size_t)(rbase+wv)*1152 + 384 + h*64;
    float s = waveSum(q[lane]*k[lane]) * 0.125f;
    if(lane==0) exs[wv] = s;
  }
  __syncthreads();
  float mx = -1e30f;
  for(int c=tid;c<500;c+=256) mx = fmaxf(mx, pr[c]);
  if(tid < NE) mx = fmaxf(mx, exs[tid]);
  mx = waveMax(mx);
  if(lane==0) r4[wv]=mx;
  __syncthreads();
  mx = fmaxf(fmaxf(r4[0],r4[1]),fmaxf(r4[2],r4[3]));
  float s=0.f;
  for(int c=tid;c<500;c+=256){ float e=expf(pr[c]-mx); pr[c]=e; s+=e; }
  if(tid < NE) s += expf(exs[tid]-mx);
  s = waveSum(s);
  __syncthreads();
  if(lane==0) r4[wv]=s;
  __syncthreads();
  float inv = 1.f/(r4[0]+r4[1]+r4[2]+r4[3]);
  // PV: wave wv handles keys j = wv, wv+4, ...; lane = output dim d
  const float* Vh = V1 + h*64;
  float acc = 0.f;
  for(int j=wv;j<500;j+=4) acc = fmaf(pr[j], Vh[(size_t)j*384 + lane], acc);
  red[wv][lane] = acc;
  __syncthreads();
  if(wv==0){
    float v = red[0][lane]+red[1][lane]+red[2][lane]+red[3][lane];
#pragma unroll
    for(int e=0;e<NE;e++)
      v = fmaf(expf(exs[e]-mx), qkv1[(size_t)(rbase+e)*1152 + 768 + h*64 + lane], v);
    O[(size_t)r*384 + h*64 + lane] = v*inv;
  }
}

// merge_seq + merge_hid + build pairs for NEXT iteration; last: compact seq + zero loss6
__global__ void merge_all(const float* __restrict__ seqOld, const float* __restrict__ fused,
                          const float* __restrict__ hidOld, const float* __restrict__ rp,
                          const int* __restrict__ idxb,
                          float* __restrict__ seqNew, float* __restrict__ hidNew,
                          float* __restrict__ pairs, int P, int last, int seqLd,
                          float* __restrict__ lossBase){
  int gid = blockIdx.x*256+threadIdx.x;
  if(last && gid < 128) lossBase[(size_t)gid*9 + 6] = 0.f;
  int nA = 128*P*384;
  if(gid < nA){
    int j = gid % 384; int rest = gid / 384; int i = rest % P; int b = rest / P;
    int id = idxb[b];
    float v = (i==id) ? fused[(size_t)b*384+j]
                      : seqOld[((size_t)b*8 + i + (i>id?1:0))*384 + j];
    seqNew[((size_t)b*seqLd+i)*384+j] = v;
    return;
  }
  if(last) return;
  gid -= nA;
  int Pn = P-1;
  int nB = 128*Pn*384;
  if(gid < nB){
    int j = gid % 384; int rest = gid / 384; int i = rest % Pn; int b = rest / Pn;
    int idx = idxb[b];
    int si = i + (i>=idx ? 1 : 0);
    hidNew[((size_t)b*7+i)*384+j] = hidOld[((size_t)b*7+si)*384+j];
    return;
  }
  gid -= nB;
  if(gid >= 256*768) return;
  int c = gid % 768; int rr = gid / 768; int b = rr>>1; int e = rr&1;
  int idx = idxb[b];
  int s = idx-1+e; s = max(0, min(s, Pn-1));
  int t = c/384, j = c%384;
  int row = s+t;   // row in NEW sequence
  float v = (row==idx) ? fused[(size_t)b*384+j]
                       : seqOld[((size_t)b*8 + row + (row>idx?1:0))*384 + j];
  pairs[gid] = v + rp[t*384+j];
}

__global__ void logits_k(const float* __restrict__ x2, const float* __restrict__ relmem,
                         const float* __restrict__ seqf, float* __restrict__ out){
  int gid = blockIdx.x*256+threadIdx.x;
  if(gid >= 256*502) return;
  int m = gid % 502; int bt = gid / 502; int b = bt>>1;
  const float* x = x2 + (size_t)bt*384;
  const float* mr = (m<500) ? relmem + (size_t)m*384 : seqf + ((size_t)b*2 + (m-500))*384;
  float s=0.f;
#pragma unroll 8
  for(int d=0;d<384;d++) s = fmaf(x[d], mr[d], s);
  out[gid] = s * 0.05103103630798288f;
}

// fused: entropy per row + pred copy for odd rows
__global__ __launch_bounds__(256)
void final_out(const float* __restrict__ L2, float* __restrict__ lossBase,
               float* __restrict__ pred){
  int row = blockIdx.x;
  const float* x = L2 + (size_t)row*502;
  int tid = threadIdx.x;
  if(row & 1){
    float* p = pred + (size_t)(row>>1)*502;
    for(int c=tid;c<502;c+=256) p[c] = x[c];
  }
  float m = -1e30f;
  for(int c=tid;c<502;c+=256) m = fmaxf(m, x[c]);
  m = waveMax(m);
  __shared__ float sm[4];
  if((tid&63)==0) sm[tid>>6]=m;
  __syncthreads();
  m = fmaxf(fmaxf(sm[0],sm[1]),fmaxf(sm[2],sm[3]));
  float s=0.f, sx=0.f;
  for(int c=tid;c<502;c+=256){ float e=expf(x[c]-m); s+=e; sx=fmaf(e,x[c],sx); }
  s = waveSum(s); sx = waveSum(sx);
  __shared__ float ps[4], px[4];
  if((tid&63)==0){ ps[tid>>6]=s; px[tid>>6]=sx; }
  __syncthreads();
  if(tid==0){
    float S = ps[0]+ps[1]+ps[2]+ps[3];
    float SX = px[0]+px[1]+px[2]+px[3];
    float ent = (m + logf(S)) - SX/S;
    int b = row>>1, t = row&1;
    lossBase[(size_t)b*9 + 7 + t] = ent;
  }
}

// ---------------- host ----------------
extern "C" void kernel_launch(void* const* d_in, const int* in_sizes, int n_in,
                              void* d_out, int out_size, void* d_ws, size_t ws_size,
                              hipStream_t stream){
  (void)in_sizes; (void)n_in; (void)out_size; (void)ws_size;
  const int*   inputs    = (const int*)  d_in[0];
  const float* emb       = (const float*)d_in[1];
  const float* rel_pos   = (const float*)d_in[2];
  const float* qkv_dyn_w = (const float*)d_in[3];
  const float* qkv_dyn_b = (const float*)d_in[4];
  const float* out_dyn_w = (const float*)d_in[5];
  const float* out_dyn_b = (const float*)d_in[6];
  const float* ln_dyn_g  = (const float*)d_in[7];
  const float* ln_dyn_b  = (const float*)d_in[8];
  const float* conv_w    = (const float*)d_in[9];
  const float* conv_b    = (const float*)d_in[10];
  const float* tl_in_w   = (const float*)d_in[11];
  const float* tl_in_b   = (const float*)d_in[12];
  const float* tl_out_w  = (const float*)d_in[13];
  const float* tl_out_b  = (const float*)d_in[14];
  const float* tl_ln1_g  = (const float*)d_in[15];
  const float* tl_ln1_b  = (const float*)d_in[16];
  const float* tl_ln2_g  = (const float*)d_in[17];
  const float* tl_ln2_b  = (const float*)d_in[18];
  const float* tl_ff1_w  = (const float*)d_in[19];
  const float* tl_ff1_b  = (const float*)d_in[20];
  const float* tl_ff2_w  = (const float*)d_in[21];
  const float* tl_ff2_b  = (const float*)d_in[22];
  const float* fc_score_w= (const float*)d_in[23];
  const float* fc_score_b= (const float*)d_in[24];
  const float* fcq_w     = (const float*)d_in[25];
  const float* fcq_b     = (const float*)d_in[26];
  const float* fck_w     = (const float*)d_in[27];
  const float* fck_b     = (const float*)d_in[28];
  const float* fcv_w     = (const float*)d_in[29];
  const float* fcv_b     = (const float*)d_in[30];
  const float* mha_in_w  = (const float*)d_in[31];
  const float* mha_in_b  = (const float*)d_in[32];
  const float* mha_out_w = (const float*)d_in[33];
  const float* mha_out_b = (const float*)d_in[34];
  const float* lnf1_g    = (const float*)d_in[35];
  const float* lnf1_b    = (const float*)d_in[36];
  const float* lnf2_g    = (const float*)d_in[37];
  const float* lnf2_b    = (const float*)d_in[38];
  const float* ff1_w     = (const float*)d_in[39];
  const float* ff1_b     = (const float*)d_in[40];
  const float* ff2_w     = (const float*)d_in[41];
  const float* ff2_b     = (const float*)d_in[42];

  float* ws = (float*)d_ws;
  size_t off = 0;
  auto Aa = [&](size_t n){ float* p = ws + off; off += n; return p; };
  float* relmem = Aa(192000);
  float* K1mem  = Aa(192000);
  float* V1f    = Aa(192000);
  float* V1l    = Aa(192000);
  float* K1padf = Aa(196608);   // [512][384]
  float* cb     = Aa(1536);
  float* cb768  = Aa(768);
  float* seqA_  = Aa(393216);
  float* seqB_  = Aa(393216);
  float* hidA_  = Aa(344064);   // [128][7][384]
  float* hidB_  = Aa(344064);
  float* fqkv1  = Aa(147456);
  float* gqkv1  = Aa(294912);
  unsigned short* SH = (unsigned short*)Aa(3317760);
  unsigned short* SL = (unsigned short*)Aa(3317760);
  float* Pp     = Aa(2359296);  // split-K partials
  float* pairs  = Aa(688128);
  float* xbuf   = Aa(688128);
  float* qkvbuf = Aa(2064384);
  float* obuf   = Aa(688128);
  float* tmpb   = Aa(688128);
  float* ffbuf  = Aa(2752512);
  float* probs2 = Aa(14336);
  int*   idxb   = (int*)Aa(128);
  float* sel    = Aa(49152);
  float* fo     = Aa(49152);
  float* fxf    = Aa(49152);
  float* ffused = Aa(49152);
  float* fffb   = Aa(196608);

  // setup-phase temps inside ffbuf
  float* sc512   = ffbuf;                // 2*500*512 = 512000
  float* Cfuse3f = ffbuf + 600000;       // 1152*384 = 442368
  float* Cvkf    = ffbuf + 1100000;      // 147456
  float* Wconvf  = ffbuf + 1300000;      // 589824
  float* VT      = tmpb;                 // 2*192*512 = 196608
  // attention temps (alias dead arenas during attention phases)
  float* Sbuf = ffbuf;                   // up to 6*256*512 = 786432
  // final-stage aliases
  float* seqf = pairs;
  float* go   = obuf;
  float* gx1  = obuf + 196608;
  float* gx2  = obuf + 294912;
  float* logitsb = qkvbuf;

  float* lossBase = (float*)d_out + 128*502;

  // split-arena segment offsets (ushort elements)
  const int o_qkvdyn=0, o_outdyn=442368, o_wconv=589824,
            o_tlin0=1179648, o_tlin1=1622016, o_tlout0=2064384, o_tlout1=2211840,
            o_tlff1_0=2359296, o_tlff1_1=2949120, o_tlff2_0=3538944, o_tlff2_1=4128768,
            o_mhaout=4718592, o_ff1=4866048, o_ff2=5455872, o_cfuse=6045696, o_cvk=6488064;
  const int split_total = 6635520;

  const float s192 = 0.07216878364870322f;  // 1/sqrt(192)

  // ---------- stage 1: relation_mem ----------
  gemm3<0><<<dim3(8,18),256,0,stream>>>(emb,384, qkv_dyn_w,384, qkvbuf,1152, qkv_dyn_b, 500,1152,384, 1.f);
  for(int h=0;h<2;h++)
    gemm3<0><<<dim3(8,8),256,0,stream>>>(qkvbuf + h*192,1152, qkvbuf + 384 + h*192,1152,
           sc512 + (size_t)h*256000,512, nullptr, 500,512,192, s192);
  softmax_rows<<<1000,256,0,stream>>>(sc512, 512, 500);
  vt_k<<<CDIV(2*192*512,256),256,0,stream>>>(qkvbuf, VT);
  for(int h=0;h<2;h++)
    gemm3<0><<<dim3(8,3),256,0,stream>>>(sc512 + (size_t)h*256000,512, VT + h*98304,512,
           obuf + h*192,384, nullptr, 500,192,512, 1.f);
  gemm3<0><<<dim3(8,6),256,0,stream>>>(obuf,384, out_dyn_w,384, xbuf,384, out_dyn_b, 500,384,384, 1.f);
  add_ln<<<500,128,0,stream>>>(emb, xbuf, relmem, ln_dyn_g, ln_dyn_b, 500, nullptr);

  // ---------- compositions ----------
  gemm_nn<<<dim3(6,6),256,0,stream>>>(mha_in_w,384,            fcq_w,384, Cfuse3f,384,          384,384,384, 1.f);
  gemm_nn<<<dim3(6,6),256,0,stream>>>(mha_in_w + 384*384,384,  fck_w,384, Cfuse3f + 147456,384, 384,384,384, 1.f);
  gemm_nn<<<dim3(6,6),256,0,stream>>>(mha_in_w + 768*384,384,  fcv_w,384, Cfuse3f + 294912,384, 384,384,384, 1.f);
  gemm_nn<<<dim3(6,6),256,0,stream>>>(mha_in_w + 768*384,384,  fck_w,384, Cvkf,384,             384,384,384, 1.f);
  compose_bias<<<6,256,0,stream>>>(mha_in_w, mha_in_b, fcq_b, fck_b, fcv_b, cb);

  // ---------- batch-invariant K/V for fuse/final ----------
  gemm3<0><<<dim3(8,6),256,0,stream>>>(relmem,384, Cfuse3f + 147456,384, K1mem,384, cb+384,  500,384,384, 1.f);
  gemm3<0><<<dim3(8,6),256,0,stream>>>(relmem,384, Cfuse3f + 294912,384, V1f,384,   cb+768,  500,384,384, 1.f);
  gemm3<0><<<dim3(8,6),256,0,stream>>>(relmem,384, Cvkf,384,            V1l,384,   cb+1152, 500,384,384, 1.f);
  pad_k1<<<CDIV(512*384,256),256,0,stream>>>(K1mem, K1padf);

  prep_conv<<<CDIV(384*384,256),256,0,stream>>>(conv_w, conv_b, Wconvf, cb768);

  // ---------- split all hot-loop weights into tile-swizzled hi/lo ----------
  {
    SplitArgs a;
    const float* srcs[NSEG] = { qkv_dyn_w, out_dyn_w, Wconvf, tl_in_w, tl_in_w + 442368,
                                tl_out_w, tl_out_w + 147456, tl_ff1_w, tl_ff1_w + 589824,
                                tl_ff2_w, tl_ff2_w + 589824, mha_out_w, ff1_w, ff2_w,
                                Cfuse3f, Cvkf };
    const int offs[NSEG+1] = { o_qkvdyn, o_outdyn, o_wconv, o_tlin0, o_tlin1, o_tlout0, o_tlout1,
                               o_tlff1_0, o_tlff1_1, o_tlff2_0, o_tlff2_1, o_mhaout, o_ff1, o_ff2,
                               o_cfuse, o_cvk, split_total };
    const int lds[NSEG] = { 384, 384, 768, 384, 384, 384, 384, 384, 384,
                            1536, 1536, 384, 384, 1536, 384, 384 };
    for(int s=0;s<NSEG;s++){
      a.src[s]=srcs[s]; a.dh[s]=SH+offs[s]; a.dl[s]=SL+offs[s]; a.start[s]=offs[s];
      a.ld[s]=lds[s];
    }
    a.start[NSEG]=split_total;
    split_all<<<CDIV(split_total,256),256,0,stream>>>(a);
  }
  seq_init<<<CDIV(128*8*384,256),256,0,stream>>>(inputs, emb, rel_pos, seqA_);

  float* seqCur = seqA_; float* seqNxt = seqB_;
  float* hidCur = hidA_; float* hidNxt = hidB_;

  // ---------- merge loop ----------
  for(int it=0; it<6; ++it){
    int P = 7 - it;
    if(it == 0){
      int N = 128*7, R2 = 2*N;   // 896 pairs, 1792 rows
      build_pairs<<<CDIV(N*768,256),256,0,stream>>>(seqCur, rel_pos, pairs, N, 7);
      gemm3s<0><<<dim3(N/64,12),256,0,stream>>>(pairs,768, SH+o_wconv,SL+o_wconv,768,
                                                xbuf,768, cb768, N,768,768);
      for(int l=0;l<2;l++){
        int oin  = l? o_tlin1  : o_tlin0;
        int oout = l? o_tlout1 : o_tlout0;
        int of1  = l? o_tlff1_1: o_tlff1_0;
        int of2  = l? o_tlff2_1: o_tlff2_0;
        gemm3s<0><<<dim3(R2/64,18),256,0,stream>>>(xbuf,384, SH+oin,SL+oin,384,
                                                   qkvbuf,1152, tl_in_b + l*1152, R2,1152,384);
        attn2_one<<<N,256,0,stream>>>(qkvbuf, obuf, N);
        gemm3s<0><<<dim3(R2/64,6),256,0,stream>>>(obuf,384, SH+oout,SL+oout,384,
                                                  tmpb,384, tl_out_b + l*384, R2,384,384);
        add_ln<<<R2,128,0,stream>>>(xbuf, tmpb, xbuf, tl_ln1_g + l*384, tl_ln1_b + l*384, R2, nullptr);
        gemm3s<1><<<dim3(R2/64,24),256,0,stream>>>(xbuf,384, SH+of1,SL+of1,384,
                                                   ffbuf,1536, tl_ff1_b + l*1536, R2,1536,384);
        gemm3s<0><<<dim3(R2/64,6),256,0,stream>>>(ffbuf,1536, SH+of2,SL+of2,1536,
                                                  tmpb,384, tl_ff2_b + l*384, R2,384,1536);
        add_ln<<<R2,128,0,stream>>>(xbuf, tmpb, xbuf, tl_ln2_g + l*384, tl_ln2_b + l*384, R2,
                                    (l==1) ? hidCur : nullptr);
      }
    } else {
      // incremental: pairs were built by previous iteration's merge_all
      const int N2 = 256, R2 = 512;
      gemm3bk<<<dim3(4,12,12),256,0,stream>>>(pairs,768,0, SH+o_wconv,SL+o_wconv,768,0,
                                              Pp, N2,768,64,12);
      reduce_k<0><<<CDIV(N2*768,256),256,0,stream>>>(Pp, xbuf, cb768, N2*768,768,768,0,12,1, 1.f);
      for(int l=0;l<2;l++){
        int oin  = l? o_tlin1  : o_tlin0;
        int oout = l? o_tlout1 : o_tlout0;
        int of1  = l? o_tlff1_1: o_tlff1_0;
        int of2  = l? o_tlff2_1: o_tlff2_0;
        gemm3s<0><<<dim3(R2/64,18),256,0,stream>>>(xbuf,384, SH+oin,SL+oin,384,
                                                   qkvbuf,1152, tl_in_b + l*1152, R2,1152,384);
        attn2_one<<<N2,256,0,stream>>>(qkvbuf, obuf, N2);
        gemm3bk<<<dim3(R2/64,6,6),256,0,stream>>>(obuf,384,0, SH+oout,SL+oout,384,0,
                                                  Pp, R2,384,64,6);
        reduce_ln<<<R2,128,0,stream>>>(Pp, xbuf, xbuf, tl_ln1_g + l*384, tl_ln1_b + l*384,
                                       tl_out_b + l*384, R2, 6);
        gemm3s<1><<<dim3(R2/64,24),256,0,stream>>>(xbuf,384, SH+of1,SL+of1,384,
                                                   ffbuf,1536, tl_ff1_b + l*1536, R2,1536,384);
        gemm3bk<<<dim3(R2/64,6,8),256,0,stream>>>(ffbuf,1536,0, SH+of2,SL+of2,1536,0,
                                                  Pp, R2,384,192,8);
        reduce_ln<<<R2,128,0,stream>>>(Pp, xbuf, xbuf, tl_ln2_g + l*384, tl_ln2_b + l*384,
                                       tl_ff2_b + l*384, R2, 8);
      }
    }
    score_select3<<<128,256,0,stream>>>(hidCur, xbuf, fc_score_w, fc_score_b, P, idxb,
                                        lossBase + it, sel, (it>0) ? 1 : 0);
    // fuse qkv: split-K
    gemm3bk<<<dim3(2,18,6),256,0,stream>>>(sel,384,0, SH+o_cfuse,SL+o_cfuse,384,0,
                                           Pp, 128,1152,64,6);
    reduce_k<0><<<CDIV(128*1152,256),256,0,stream>>>(Pp, fqkv1, cb, 128*1152,1152,1152,0,6,1, 1.f);
    // attention: scores GEMM + fused softmax/PV tail
    gemm3z<<<dim3(2,8,6),256,0,stream>>>(fqkv1,1152,64, K1padf,384,64,
                                         Sbuf,512,128*512, 128,512,64, 0.125f);
    attn_tail<1><<<768,256,0,stream>>>(Sbuf, fqkv1, V1f, fo, 128);
    // mha_out: split-K + fused residual-LN
    gemm3bk<<<dim3(2,6,6),256,0,stream>>>(fo,384,0, SH+o_mhaout,SL+o_mhaout,384,0,
                                          Pp, 128,384,64,6);
    reduce_ln<<<128,128,0,stream>>>(Pp, sel, fxf, lnf1_g, lnf1_b, mha_out_b, 128, 6);
    // ff1: split-K + GELU
    gemm3bk<<<dim3(2,24,6),256,0,stream>>>(fxf,384,0, SH+o_ff1,SL+o_ff1,384,0,
                                           Pp, 128,1536,64,6);
    reduce_k<1><<<CDIV(128*1536,256),256,0,stream>>>(Pp, fffb, ff1_b, 128*1536,1536,1536,0,6,1, 1.f);
    // ff2: split-K + fused residual-LN
    gemm3bk<<<dim3(2,6,24),256,0,stream>>>(fffb,1536,0, SH+o_ff2,SL+o_ff2,1536,0,
                                           Pp, 128,384,64,24);
    reduce_ln<<<128,128,0,stream>>>(Pp, fxf, ffused, lnf2_g, lnf2_b, ff2_b, 128, 24);
    // merged seq/hid update + next-iteration pair build (last: compact into seqf)
    if(it < 5){
      int total = 128*P*384 + 128*(P-1)*384 + 256*768;
      merge_all<<<CDIV(total,256),256,0,stream>>>(seqCur, ffused, hidCur, rel_pos, idxb,
                                                  seqNxt, hidNxt, pairs, P, 0, 8, lossBase);
      float* t1 = seqCur; seqCur = seqNxt; seqNxt = t1;
      float* t2 = hidCur; hidCur = hidNxt; hidNxt = t2;
    } else {
      int total = 128*P*384;
      merge_all<<<CDIV(total,256),256,0,stream>>>(seqCur, ffused, hidCur, rel_pos, idxb,
                                                  seqf, hidNxt, pairs, P, 1, 2, lossBase);
    }
  }

  // ---------- final stage (Lf = 2): seqf already compact [256][384] ----------
  gemm3bk<<<dim3(4,12,6),256,0,stream>>>(seqf,384,0, SH+o_cfuse,SL+o_cfuse,384,0,
                                         Pp, 256,768,64,6);
  reduce_k<0><<<CDIV(256*768,256),256,0,stream>>>(Pp, gqkv1, cb, 256*768,768,1152,0,6,1, 1.f);
  gemm3bk<<<dim3(4,6,6),256,0,stream>>>(seqf,384,0, SH+o_cvk,SL+o_cvk,384,0,
                                        Pp, 256,384,64,6);
  reduce_k<0><<<CDIV(256*384,256),256,0,stream>>>(Pp, gqkv1+768, cb+1152, 256*384,384,1152,0,6,1, 1.f);
  gemm3z<<<dim3(4,8,6),256,0,stream>>>(gqkv1,1152,64, K1padf,384,64,
                                       Sbuf,512,256*512, 256,512,64, 0.125f);
  attn_tail<2><<<1536,256,0,stream>>>(Sbuf, gqkv1, V1l, go, 256);
  gemm3bk<<<dim3(4,6,6),256,0,stream>>>(go,384,0, SH+o_mhaout,SL+o_mhaout,384,0,
                                        Pp, 256,384,64,6);
  reduce_ln<<<256,128,0,stream>>>(Pp, seqf, gx1, lnf1_g, lnf1_b, mha_out_b, 256, 6);
  gemm3bk<<<dim3(4,24,6),256,0,stream>>>(gx1,384,0, SH+o_ff1,SL+o_ff1,384,0,
                                         Pp, 256,1536,64,6);
  reduce_k<1><<<CDIV(256*1536,256),256,0,stream>>>(Pp, ffbuf, ff1_b, 256*1536,1536,1536,0,6,1, 1.f);
  gemm3bk<<<dim3(4,6,24),256,0,stream>>>(ffbuf,1536,0, SH+o_ff2,SL+o_ff2,1536,0,
                                         Pp, 256,384,64,24);
  reduce_ln<<<256,128,0,stream>>>(Pp, gx1, gx2, lnf2_g, lnf2_b, ff2_b, 256, 24);
  logits_k<<<CDIV(256*502,256),256,0,stream>>>(gx2, relmem, seqf, logitsb);
  final_out<<<256,256,0,stream>>>(logitsb, lossBase, (float*)d_out);
}

// Round 15
// 1709.797 us; speedup vs baseline: 1.0980x; 1.0980x over previous
//
#include <hip/hip_runtime.h>

#define CDIV(a,b) (((a)+(b)-1)/(b))

typedef __bf16 bf16x8 __attribute__((ext_vector_type(8)));
typedef float  f32x4  __attribute__((ext_vector_type(4)));
#define MFMA16(a,b,c) __builtin_amdgcn_mfma_f32_16x16x32_bf16(a,b,c,0,0,0)

// async 16B global->LDS copy: per-lane global addr, wave-uniform LDS base
__device__ __forceinline__ void ldst16(const unsigned short* g, unsigned short* l){
  __builtin_amdgcn_global_load_lds(
      (const __attribute__((address_space(1))) unsigned int*)g,
      (__attribute__((address_space(3))) unsigned int*)l, 16, 0, 0);
}

// ---------------- wave/block reductions ----------------
__device__ __forceinline__ float waveSum(float v){
#pragma unroll
  for(int o=32;o;o>>=1) v += __shfl_xor(v,o);
  return v;
}
__device__ __forceinline__ float waveMax(float v){
#pragma unroll
  for(int o=32;o;o>>=1) v = fmaxf(v,__shfl_xor(v,o));
  return v;
}

// ---------------- bf16 split helpers ----------------
__device__ __forceinline__ unsigned short f2bf(float f){
  unsigned u = __float_as_uint(f);
  u += 0x7FFFu + ((u>>16)&1u);
  return (unsigned short)(u>>16);
}
__device__ __forceinline__ float bf2f(unsigned short h){
  return __uint_as_float(((unsigned)h)<<16);
}
__device__ __forceinline__ void pack8(const float4& x, const float4& y,
                                      uint4& hi, uint4& lo){
  float v[8] = {x.x,x.y,x.z,x.w,y.x,y.y,y.z,y.w};
  unsigned short h[8], l[8];
#pragma unroll
  for(int i=0;i<8;i++){
    h[i] = f2bf(v[i]);
    l[i] = f2bf(v[i] - bf2f(h[i]));
  }
  hi = make_uint4((unsigned)h[0]|((unsigned)h[1]<<16), (unsigned)h[2]|((unsigned)h[3]<<16),
                  (unsigned)h[4]|((unsigned)h[5]<<16), (unsigned)h[6]|((unsigned)h[7]<<16));
  lo = make_uint4((unsigned)l[0]|((unsigned)l[1]<<16), (unsigned)l[2]|((unsigned)l[3]<<16),
                  (unsigned)l[4]|((unsigned)l[5]<<16), (unsigned)l[6]|((unsigned)l[7]<<16));
}

__device__ __forceinline__ bf16x8 ldsfrag(const unsigned short* base, int row, int kb){
  int off = (row<<7) + (kb<<1);
  off ^= (row&7)<<4;
  return *reinterpret_cast<const bf16x8*>(reinterpret_cast<const char*>(base) + off);
}

// ---------------- MFMA bf16x3 NT GEMM, f32 W (setup paths) ----------------
template<int ACT>
__global__ __launch_bounds__(256)
void gemm3(const float* __restrict__ A, int lda,
           const float* __restrict__ W, int ldw,
           float* __restrict__ C, int ldc,
           const float* __restrict__ bias, int M, int N, int K, float scale)
{
  __shared__ unsigned short AsH[64*64];
  __shared__ unsigned short AsL[64*64];
  __shared__ unsigned short WsH[64*64];
  __shared__ unsigned short WsL[64*64];
  const int tid  = threadIdx.x;
  const int bm   = blockIdx.x*64, bn = blockIdx.y*64;
  const int lane = tid & 63, wid = tid >> 6;
  const int wm   = (wid&1)*32, wn = (wid>>1)*32;
  const int r0   = tid>>3;
  const int kq   = (tid&7)*8;

  float4 gA[2][2], gW[2][2];
  auto loadG = [&](int k0){
#pragma unroll
    for(int i=0;i<2;i++){
      int r = r0 + i*32;
      if(bm+r < M){
        const float* pa = A + (size_t)(bm+r)*lda + k0 + kq;
        gA[i][0] = *reinterpret_cast<const float4*>(pa);
        gA[i][1] = *reinterpret_cast<const float4*>(pa+4);
      } else {
        gA[i][0] = make_float4(0.f,0.f,0.f,0.f);
        gA[i][1] = make_float4(0.f,0.f,0.f,0.f);
      }
      const float* pw = W + (size_t)(bn+r)*ldw + k0 + kq;
      gW[i][0] = *reinterpret_cast<const float4*>(pw);
      gW[i][1] = *reinterpret_cast<const float4*>(pw+4);
    }
  };
  auto writeL = [&](){
#pragma unroll
    for(int i=0;i<2;i++){
      int r = r0 + i*32;
      int off = (r<<7) + (tid&7)*16;
      off ^= (r&7)<<4;
      uint4 hi, lo;
      pack8(gA[i][0], gA[i][1], hi, lo);
      *reinterpret_cast<uint4*>(reinterpret_cast<char*>(AsH) + off) = hi;
      *reinterpret_cast<uint4*>(reinterpret_cast<char*>(AsL) + off) = lo;
      pack8(gW[i][0], gW[i][1], hi, lo);
      *reinterpret_cast<uint4*>(reinterpret_cast<char*>(WsH) + off) = hi;
      *reinterpret_cast<uint4*>(reinterpret_cast<char*>(WsL) + off) = lo;
    }
  };

  f32x4 acc[2][2];
#pragma unroll
  for(int mi=0;mi<2;mi++)
#pragma unroll
    for(int ni=0;ni<2;ni++) acc[mi][ni] = f32x4{0.f,0.f,0.f,0.f};

  loadG(0);
  for(int k0=0; k0<K; k0+=64){
    __syncthreads();
    writeL();
    __syncthreads();
    if(k0+64 < K) loadG(k0+64);
    const int lk = (lane>>4)*8;
    const int lc = lane&15;
#pragma unroll
    for(int kk=0; kk<2; kk++){
      int kb = kk*32 + lk;
      bf16x8 aH[2], aL[2], bH[2], bL[2];
#pragma unroll
      for(int m=0;m<2;m++){
        aH[m] = ldsfrag(AsH, wm + lc + m*16, kb);
        aL[m] = ldsfrag(AsL, wm + lc + m*16, kb);
        bH[m] = ldsfrag(WsH, wn + lc + m*16, kb);
        bL[m] = ldsfrag(WsL, wn + lc + m*16, kb);
      }
#pragma unroll
      for(int mi=0;mi<2;mi++)
#pragma unroll
        for(int ni=0;ni<2;ni++){
          acc[mi][ni] = MFMA16(aH[mi], bH[ni], acc[mi][ni]);
          acc[mi][ni] = MFMA16(aH[mi], bL[ni], acc[mi][ni]);
          acc[mi][ni] = MFMA16(aL[mi], bH[ni], acc[mi][ni]);
        }
    }
  }

  const int lr = lane>>4, lc = lane&15;
#pragma unroll
  for(int mi=0;mi<2;mi++)
#pragma unroll
    for(int ni=0;ni<2;ni++)
#pragma unroll
      for(int r=0;r<4;r++){
        int row = bm + wm + mi*16 + lr*4 + r;
        if(row>=M) continue;
        int col = bn + wn + ni*16 + lc;
        float v = acc[mi][ni][r]*scale + (bias ? bias[col] : 0.f);
        if(ACT==1) v = 0.5f*v*(1.f+erff(v*0.70710678118654752f));
        C[(size_t)row*ldc+col] = v;
      }
}

// ---------------- batched-z MFMA bf16x3 NT GEMM (attention scores) ----------------
__global__ __launch_bounds__(256)
void gemm3z(const float* A0, int lda, int sAz,
            const float* W0, int ldw, int sWz,
            float* C0, int ldc, int sCz,
            int M, int N, int K, float scale)
{
  const float* A = A0 + (size_t)blockIdx.z*sAz;
  const float* W = W0 + (size_t)blockIdx.z*sWz;
  float*       C = C0 + (size_t)blockIdx.z*sCz;
  __shared__ unsigned short AsH[64*64];
  __shared__ unsigned short AsL[64*64];
  __shared__ unsigned short WsH[64*64];
  __shared__ unsigned short WsL[64*64];
  const int tid  = threadIdx.x;
  const int bm   = blockIdx.x*64, bn = blockIdx.y*64;
  const int lane = tid & 63, wid = tid >> 6;
  const int wm   = (wid&1)*32, wn = (wid>>1)*32;
  const int r0   = tid>>3;
  const int kq   = (tid&7)*8;

  float4 gA[2][2], gW[2][2];
  auto loadG = [&](int k0){
#pragma unroll
    for(int i=0;i<2;i++){
      int r = r0 + i*32;
      if(bm+r < M){
        const float* pa = A + (size_t)(bm+r)*lda + k0 + kq;
        gA[i][0] = *reinterpret_cast<const float4*>(pa);
        gA[i][1] = *reinterpret_cast<const float4*>(pa+4);
      } else {
        gA[i][0] = make_float4(0.f,0.f,0.f,0.f);
        gA[i][1] = make_float4(0.f,0.f,0.f,0.f);
      }
      const float* pw = W + (size_t)(bn+r)*ldw + k0 + kq;
      gW[i][0] = *reinterpret_cast<const float4*>(pw);
      gW[i][1] = *reinterpret_cast<const float4*>(pw+4);
    }
  };
  auto writeL = [&](){
#pragma unroll
    for(int i=0;i<2;i++){
      int r = r0 + i*32;
      int off = (r<<7) + (tid&7)*16;
      off ^= (r&7)<<4;
      uint4 hi, lo;
      pack8(gA[i][0], gA[i][1], hi, lo);
      *reinterpret_cast<uint4*>(reinterpret_cast<char*>(AsH) + off) = hi;
      *reinterpret_cast<uint4*>(reinterpret_cast<char*>(AsL) + off) = lo;
      pack8(gW[i][0], gW[i][1], hi, lo);
      *reinterpret_cast<uint4*>(reinterpret_cast<char*>(WsH) + off) = hi;
      *reinterpret_cast<uint4*>(reinterpret_cast<char*>(WsL) + off) = lo;
    }
  };

  f32x4 acc[2][2];
#pragma unroll
  for(int mi=0;mi<2;mi++)
#pragma unroll
    for(int ni=0;ni<2;ni++) acc[mi][ni] = f32x4{0.f,0.f,0.f,0.f};

  loadG(0);
  for(int k0=0; k0<K; k0+=64){
    __syncthreads();
    writeL();
    __syncthreads();
    if(k0+64 < K) loadG(k0+64);
    const int lk = (lane>>4)*8;
    const int lc = lane&15;
#pragma unroll
    for(int kk=0; kk<2; kk++){
      int kb = kk*32 + lk;
      bf16x8 aH[2], aL[2], bH[2], bL[2];
#pragma unroll
      for(int m=0;m<2;m++){
        aH[m] = ldsfrag(AsH, wm + lc + m*16, kb);
        aL[m] = ldsfrag(AsL, wm + lc + m*16, kb);
        bH[m] = ldsfrag(WsH, wn + lc + m*16, kb);
        bL[m] = ldsfrag(WsL, wn + lc + m*16, kb);
      }
#pragma unroll
      for(int mi=0;mi<2;mi++)
#pragma unroll
        for(int ni=0;ni<2;ni++){
          acc[mi][ni] = MFMA16(aH[mi], bH[ni], acc[mi][ni]);
          acc[mi][ni] = MFMA16(aH[mi], bL[ni], acc[mi][ni]);
          acc[mi][ni] = MFMA16(aL[mi], bH[ni], acc[mi][ni]);
        }
    }
  }

  const int lr = lane>>4, lc = lane&15;
#pragma unroll
  for(int mi=0;mi<2;mi++)
#pragma unroll
    for(int ni=0;ni<2;ni++)
#pragma unroll
      for(int r=0;r<4;r++){
        int row = bm + wm + mi*16 + lr*4 + r;
        if(row>=M) continue;
        int col = bn + wn + ni*16 + lc;
        C[(size_t)row*ldc+col] = acc[mi][ni][r]*scale;
      }
}

// ---------------- MFMA bf16x3 NT GEMM, tile-swizzled pre-split W ----------------
template<int ACT>
__global__ __launch_bounds__(256)
void gemm3s(const float* __restrict__ A, int lda,
            const unsigned short* __restrict__ WH,
            const unsigned short* __restrict__ WL, int ldw,
            float* __restrict__ C, int ldc,
            const float* __restrict__ bias, int M, int N, int K)
{
  __shared__ unsigned short AsH[4096];
  __shared__ unsigned short AsL[4096];
  __shared__ unsigned short WsH0[4096], WsL0[4096];
  __shared__ unsigned short WsH1[4096], WsL1[4096];
  const int tid  = threadIdx.x;
  const int bm   = blockIdx.x*64, bn = blockIdx.y*64;
  const int lane = tid & 63, wid = tid >> 6;
  const int wm   = (wid&1)*32, wn = (wid>>1)*32;
  const int r0   = tid>>3;
  const int kq   = (tid&7)*8;
  const int KT   = ldw >> 6;
  const unsigned short* WHt = WH + (size_t)(bn>>6)*KT*4096;
  const unsigned short* WLt = WL + (size_t)(bn>>6)*KT*4096;
  const int wbase = wid*1024;

  float4 gA[2][2];
  auto loadGA = [&](int k0){
#pragma unroll
    for(int i=0;i<2;i++){
      int r = r0 + i*32;
      if(bm+r < M){
        const float* pa = A + (size_t)(bm+r)*lda + k0 + kq;
        gA[i][0] = *reinterpret_cast<const float4*>(pa);
        gA[i][1] = *reinterpret_cast<const float4*>(pa+4);
      } else {
        gA[i][0] = make_float4(0.f,0.f,0.f,0.f);
        gA[i][1] = make_float4(0.f,0.f,0.f,0.f);
      }
    }
  };
  auto writeLA = [&](){
#pragma unroll
    for(int i=0;i<2;i++){
      int r = r0 + i*32;
      int off = (r<<7) + (tid&7)*16;
      off ^= (r&7)<<4;
      uint4 hi, lo;
      pack8(gA[i][0], gA[i][1], hi, lo);
      *reinterpret_cast<uint4*>(reinterpret_cast<char*>(AsH) + off) = hi;
      *reinterpret_cast<uint4*>(reinterpret_cast<char*>(AsL) + off) = lo;
    }
  };
  auto asyncW = [&](int kt, unsigned short* dH, unsigned short* dL){
    const unsigned short* gh = WHt + (size_t)kt*4096 + wbase + lane*8;
    const unsigned short* gl = WLt + (size_t)kt*4096 + wbase + lane*8;
    ldst16(gh,       dH + wbase);
    ldst16(gh + 512, dH + wbase + 512);
    ldst16(gl,       dL + wbase);
    ldst16(gl + 512, dL + wbase + 512);
  };

  f32x4 acc[2][2];
#pragma unroll
  for(int mi=0;mi<2;mi++)
#pragma unroll
    for(int ni=0;ni<2;ni++) acc[mi][ni] = f32x4{0.f,0.f,0.f,0.f};

  auto compute = [&](const unsigned short* Wh, const unsigned short* Wl){
    const int lk = (lane>>4)*8;
    const int lc = lane&15;
#pragma unroll
    for(int kk=0; kk<2; kk++){
      int kb = kk*32 + lk;
      bf16x8 aH[2], aL[2], bH[2], bL[2];
#pragma unroll
      for(int m=0;m<2;m++){
        aH[m] = ldsfrag(AsH, wm + lc + m*16, kb);
        aL[m] = ldsfrag(AsL, wm + lc + m*16, kb);
        bH[m] = ldsfrag(Wh, wn + lc + m*16, kb);
        bL[m] = ldsfrag(Wl, wn + lc + m*16, kb);
      }
#pragma unroll
      for(int mi=0;mi<2;mi++)
#pragma unroll
        for(int ni=0;ni<2;ni++){
          acc[mi][ni] = MFMA16(aH[mi], bH[ni], acc[mi][ni]);
          acc[mi][ni] = MFMA16(aH[mi], bL[ni], acc[mi][ni]);
          acc[mi][ni] = MFMA16(aL[mi], bH[ni], acc[mi][ni]);
        }
    }
  };

  asyncW(0, WsH0, WsL0);
  loadGA(0);
  int k0 = 0, kt = 0;
  while(true){
    __syncthreads();
    writeLA();
    __syncthreads();
    if(k0+64 < K){ asyncW(kt+1, WsH1, WsL1); loadGA(k0+64); }
    compute(WsH0, WsL0);
    k0 += 64; kt++;
    if(k0 >= K) break;
    __syncthreads();
    writeLA();
    __syncthreads();
    if(k0+64 < K){ asyncW(kt+1, WsH0, WsL0); loadGA(k0+64); }
    compute(WsH1, WsL1);
    k0 += 64; kt++;
    if(k0 >= K) break;
  }

  const int lr = lane>>4, lc = lane&15;
#pragma unroll
  for(int mi=0;mi<2;mi++)
#pragma unroll
    for(int ni=0;ni<2;ni++)
#pragma unroll
      for(int r=0;r<4;r++){
        int row = bm + wm + mi*16 + lr*4 + r;
        if(row>=M) continue;
        int col = bn + wn + ni*16 + lc;
        float v = acc[mi][ni][r] + (bias ? bias[col] : 0.f);
        if(ACT==1) v = 0.5f*v*(1.f+erff(v*0.70710678118654752f));
        C[(size_t)row*ldc+col] = v;
      }
}

// ---------------- split-K batched MFMA GEMM, tile-swizzled pre-split W -----------
__global__ __launch_bounds__(256)
void gemm3bk(const float* __restrict__ A0, int lda, int sAz,
             const unsigned short* __restrict__ WH0,
             const unsigned short* __restrict__ WL0, int ldw, int sWz,
             float* __restrict__ Cp, int M, int N, int KLEN, int KS)
{
  __shared__ unsigned short AsH[4096];
  __shared__ unsigned short AsL[4096];
  __shared__ unsigned short WsH0[4096], WsL0[4096];
  __shared__ unsigned short WsH1[4096], WsL1[4096];
  const int z  = blockIdx.z;
  const int bz = z / KS, ks = z - bz*KS;
  const float* A = A0 + (size_t)bz*sAz;
  const unsigned short* WH = WH0 + (size_t)bz*sWz;
  const unsigned short* WL = WL0 + (size_t)bz*sWz;
  const int kbeg = ks*KLEN, kend = kbeg + KLEN;
  const int tid  = threadIdx.x;
  const int bm   = blockIdx.x*64, bn = blockIdx.y*64;
  const int lane = tid & 63, wid = tid >> 6;
  const int wm   = (wid&1)*32, wn = (wid>>1)*32;
  const int r0   = tid>>3;
  const int kq   = (tid&7)*8;
  const int KT   = ldw >> 6;
  const unsigned short* WHt = WH + (size_t)(bn>>6)*KT*4096;
  const unsigned short* WLt = WL + (size_t)(bn>>6)*KT*4096;
  const int wbase = wid*1024;

  float4 gA[2][2];
  auto loadGA = [&](int k0){
#pragma unroll
    for(int i=0;i<2;i++){
      int r = r0 + i*32;
      if(bm+r < M){
        const float* pa = A + (size_t)(bm+r)*lda + k0 + kq;
        gA[i][0] = *reinterpret_cast<const float4*>(pa);
        gA[i][1] = *reinterpret_cast<const float4*>(pa+4);
      } else {
        gA[i][0] = make_float4(0.f,0.f,0.f,0.f);
        gA[i][1] = make_float4(0.f,0.f,0.f,0.f);
      }
    }
  };
  auto writeLA = [&](){
#pragma unroll
    for(int i=0;i<2;i++){
      int r = r0 + i*32;
      int off = (r<<7) + (tid&7)*16;
      off ^= (r&7)<<4;
      uint4 hi, lo;
      pack8(gA[i][0], gA[i][1], hi, lo);
      *reinterpret_cast<uint4*>(reinterpret_cast<char*>(AsH) + off) = hi;
      *reinterpret_cast<uint4*>(reinterpret_cast<char*>(AsL) + off) = lo;
    }
  };
  auto asyncW = [&](int kt, unsigned short* dH, unsigned short* dL){
    const unsigned short* gh = WHt + (size_t)kt*4096 + wbase + lane*8;
    const unsigned short* gl = WLt + (size_t)kt*4096 + wbase + lane*8;
    ldst16(gh,       dH + wbase);
    ldst16(gh + 512, dH + wbase + 512);
    ldst16(gl,       dL + wbase);
    ldst16(gl + 512, dL + wbase + 512);
  };

  f32x4 acc[2][2];
#pragma unroll
  for(int mi=0;mi<2;mi++)
#pragma unroll
    for(int ni=0;ni<2;ni++) acc[mi][ni] = f32x4{0.f,0.f,0.f,0.f};

  auto compute = [&](const unsigned short* Wh, const unsigned short* Wl){
    const int lk = (lane>>4)*8;
    const int lc = lane&15;
#pragma unroll
    for(int kk=0; kk<2; kk++){
      int kb = kk*32 + lk;
      bf16x8 aH[2], aL[2], bH[2], bL[2];
#pragma unroll
      for(int m=0;m<2;m++){
        aH[m] = ldsfrag(AsH, wm + lc + m*16, kb);
        aL[m] = ldsfrag(AsL, wm + lc + m*16, kb);
        bH[m] = ldsfrag(Wh, wn + lc + m*16, kb);
        bL[m] = ldsfrag(Wl, wn + lc + m*16, kb);
      }
#pragma unroll
      for(int mi=0;mi<2;mi++)
#pragma unroll
        for(int ni=0;ni<2;ni++){
          acc[mi][ni] = MFMA16(aH[mi], bH[ni], acc[mi][ni]);
          acc[mi][ni] = MFMA16(aH[mi], bL[ni], acc[mi][ni]);
          acc[mi][ni] = MFMA16(aL[mi], bH[ni], acc[mi][ni]);
        }
    }
  };

  asyncW(kbeg>>6, WsH0, WsL0);
  loadGA(kbeg);
  int k0 = kbeg, kt = kbeg>>6;
  while(true){
    __syncthreads();
    writeLA();
    __syncthreads();
    if(k0+64 < kend){ asyncW(kt+1, WsH1, WsL1); loadGA(k0+64); }
    compute(WsH0, WsL0);
    k0 += 64; kt++;
    if(k0 >= kend) break;
    __syncthreads();
    writeLA();
    __syncthreads();
    if(k0+64 < kend){ asyncW(kt+1, WsH0, WsL0); loadGA(k0+64); }
    compute(WsH1, WsL1);
    k0 += 64; kt++;
    if(k0 >= kend) break;
  }

  float* Cpz = Cp + (size_t)z*M*N;
  const int lr = lane>>4, lc = lane&15;
#pragma unroll
  for(int mi=0;mi<2;mi++)
#pragma unroll
    for(int ni=0;ni<2;ni++)
#pragma unroll
      for(int r=0;r<4;r++){
        int row = bm + wm + mi*16 + lr*4 + r;
        if(row>=M) continue;
        int col = bn + wn + ni*16 + lc;
        Cpz[(size_t)row*N+col] = acc[mi][ni][r];
      }
}

// out[b*sCz + m*ldc + n] = act(scale * sum_ks Cp[(b*KS+ks)*MN + e] + bias[n])
template<int ACT>
__global__ __launch_bounds__(256)
void reduce_k(const float* __restrict__ Cp, float* __restrict__ C,
              const float* __restrict__ bias, int MN, int N, int ldc,
              int sCz, int KS, int NB, float scale)
{
  int gid = blockIdx.x*256+threadIdx.x;
  if(gid >= NB*MN) return;
  int b = gid / MN, e = gid - b*MN;
  int m = e / N, n = e - m*N;
  const float* p = Cp + (size_t)b*KS*MN + e;
  float s = 0.f;
  for(int k=0;k<KS;k++) s += p[(size_t)k*MN];
  s = s*scale + (bias ? bias[n] : 0.f);
  if(ACT==1) s = 0.5f*s*(1.f+erff(s*0.70710678118654752f));
  C[(size_t)b*sCz + (size_t)m*ldc + n] = s;
}

// fused split-K reduce + bias + residual + LayerNorm (N=384), block per row
__global__ __launch_bounds__(128)
void reduce_ln(const float* __restrict__ Pp, const float* __restrict__ X,
               float* __restrict__ O, const float* __restrict__ g,
               const float* __restrict__ be, const float* __restrict__ bias,
               int M, int KS)
{
  int row = blockIdx.x;
  if(row>=M) return;
  int tid = threadIdx.x;
  const float* x = X + (size_t)row*384;
  float* o = O + (size_t)row*384;
  float v[3]; float s=0.f;
#pragma unroll
  for(int i=0;i<3;i++){
    int c = tid + i*128;
    float t = bias ? bias[c] : 0.f;
    const float* p = Pp + (size_t)row*384 + c;
    for(int k=0;k<KS;k++) t += p[(size_t)k*M*384];
    v[i] = x[c] + t; s += v[i];
  }
  s = waveSum(s);
  __shared__ float p1[2];
  if((tid&63)==0) p1[tid>>6]=s;
  __syncthreads();
  float mean = (p1[0]+p1[1])*(1.f/384.f);
  float vs=0.f;
#pragma unroll
  for(int i=0;i<3;i++){ float d=v[i]-mean; vs += d*d; }
  vs = waveSum(vs);
  __shared__ float p2[2];
  if((tid&63)==0) p2[tid>>6]=vs;
  __syncthreads();
  float rstd = rsqrtf((p2[0]+p2[1])*(1.f/384.f) + 1e-5f);
#pragma unroll
  for(int i=0;i<3;i++){ int c = tid + i*128; o[c] = (v[i]-mean)*rstd*g[c] + be[c]; }
}

// ---------------- f32 NN GEMM (setup compositions) ----------------
__global__ __launch_bounds__(256)
void gemm_nn(const float* __restrict__ A, int lda,
             const float* __restrict__ Bm, int ldb,
             float* __restrict__ C, int ldc,
             int M, int N, int K, float scale)
{
  __shared__ float As[16][68];
  __shared__ float Bs[16][68];
  const int bm = blockIdx.x*64, bn = blockIdx.y*64;
  const int tid = threadIdx.x;
  const int lr = tid>>2;
  const int kq = (tid&3)<<2;
  const int kr = tid>>4;
  const int nq = (tid&15)<<2;
  const int tx = tid&15, ty = tid>>4;
  float acc[4][4] = {};
  for(int k0=0;k0<K;k0+=16){
    float4 av = make_float4(0.f,0.f,0.f,0.f), bv = make_float4(0.f,0.f,0.f,0.f);
    if(bm+lr < M && k0+kq < K) av = *reinterpret_cast<const float4*>(A + (size_t)(bm+lr)*lda + k0+kq);
    if(k0+kr < K && bn+nq < N) bv = *reinterpret_cast<const float4*>(Bm + (size_t)(k0+kr)*ldb + bn+nq);
    As[kq+0][lr]=av.x; As[kq+1][lr]=av.y; As[kq+2][lr]=av.z; As[kq+3][lr]=av.w;
    Bs[kr][nq+0]=bv.x; Bs[kr][nq+1]=bv.y; Bs[kr][nq+2]=bv.z; Bs[kr][nq+3]=bv.w;
    __syncthreads();
#pragma unroll
    for(int k=0;k<16;k++){
      float4 a4 = *reinterpret_cast<const float4*>(&As[k][ty<<2]);
      float4 b4 = *reinterpret_cast<const float4*>(&Bs[k][tx<<2]);
      float aa[4]={a4.x,a4.y,a4.z,a4.w};
      float bb[4]={b4.x,b4.y,b4.z,b4.w};
#pragma unroll
      for(int i=0;i<4;i++)
#pragma unroll
        for(int j=0;j<4;j++) acc[i][j] = fmaf(aa[i],bb[j],acc[i][j]);
    }
    __syncthreads();
  }
#pragma unroll
  for(int i=0;i<4;i++){
    int row = bm + (ty<<2) + i;
    if(row>=M) continue;
#pragma unroll
    for(int j=0;j<4;j++){
      int col = bn + (tx<<2) + j;
      if(col>=N) continue;
      C[(size_t)row*ldc+col]=acc[i][j]*scale;
    }
  }
}

// ---------------- LayerNorm(x + t), row-per-block; optional hid extract ----------
__global__ __launch_bounds__(128)
void add_ln(const float* __restrict__ X, const float* __restrict__ T,
            float* __restrict__ O, const float* __restrict__ g,
            const float* __restrict__ be, int M, float* __restrict__ hid)
{
  int row = blockIdx.x;
  if(row>=M) return;
  const float* x = X + (size_t)row*384;
  const float* t = T + (size_t)row*384;
  float* o = O + (size_t)row*384;
  int tid = threadIdx.x;
  float v[3]; float s=0.f;
#pragma unroll
  for(int i=0;i<3;i++){ int c = tid + i*128; v[i] = x[c] + t[c]; s += v[i]; }
  s = waveSum(s);
  __shared__ float p1[2];
  if((tid&63)==0) p1[tid>>6]=s;
  __syncthreads();
  float mean = (p1[0]+p1[1])*(1.f/384.f);
  float vs=0.f;
#pragma unroll
  for(int i=0;i<3;i++){ float d=v[i]-mean; vs += d*d; }
  vs = waveSum(vs);
  __shared__ float p2[2];
  if((tid&63)==0) p2[tid>>6]=vs;
  __syncthreads();
  float rstd = rsqrtf((p2[0]+p2[1])*(1.f/384.f) + 1e-5f);
#pragma unroll
  for(int i=0;i<3;i++){
    int c = tid + i*128;
    float r = (v[i]-mean)*rstd*g[c] + be[c];
    o[c] = r;
    if(hid && (row&1)) hid[(size_t)(row>>1)*384 + c] = r;
  }
}

// ---------------- row softmax with ld + zero-pad tail ----------------
__global__ __launch_bounds__(256)
void softmax_rows(float* __restrict__ X, int ld, int cols)
{
  float* x = X + (size_t)blockIdx.x*ld;
  int tid = threadIdx.x;
  float m = -1e30f;
  for(int c=tid;c<cols;c+=256) m = fmaxf(m, x[c]);
  m = waveMax(m);
  __shared__ float sm[4];
  if((tid&63)==0) sm[tid>>6]=m;
  __syncthreads();
  m = fmaxf(fmaxf(sm[0],sm[1]),fmaxf(sm[2],sm[3]));
  float s=0.f;
  for(int c=tid;c<cols;c+=256){ float e = expf(x[c]-m); x[c]=e; s+=e; }
  s = waveSum(s);
  __shared__ float ss[4];
  if((tid&63)==0) ss[tid>>6]=s;
  __syncthreads();
  s = ss[0]+ss[1]+ss[2]+ss[3];
  float inv = 1.f/s;
  for(int c=tid;c<cols;c+=256) x[c]*=inv;
  for(int c=cols+tid;c<ld;c+=256) x[c]=0.f;
}

// ---------------- setup kernels ----------------
__global__ void prep_conv(const float* __restrict__ cw, const float* __restrict__ cb,
                          float* __restrict__ Wc, float* __restrict__ cb768){
  int gid = blockIdx.x*256+threadIdx.x;
  if(gid >= 384*384) return;
  int i = gid % 384, o = gid / 384;
  const float* w = cw + (size_t)gid*3;
  Wc[(size_t)o*768 + i]            = w[1];
  Wc[(size_t)o*768 + 384 + i]      = w[2];
  Wc[(size_t)(384+o)*768 + i]      = w[0];
  Wc[(size_t)(384+o)*768 + 384 + i]= w[1];
  if(gid < 768) cb768[gid] = cb[gid % 384];
}

__global__ void vt_k(const float* __restrict__ qkv, float* __restrict__ VT){
  int gid = blockIdx.x*256+threadIdx.x;
  if(gid >= 2*192*512) return;
  int k = gid & 511; int n = (gid>>9) % 192; int h = gid / 98304;
  VT[gid] = (k<500) ? qkv[(size_t)k*1152 + 768 + h*192 + n] : 0.f;
}

// fused: pad K1 (512 rows) + build both transposed V operands
__global__ void prep_attn(const float* __restrict__ K1, const float* __restrict__ Vf,
                          const float* __restrict__ Vl, float* __restrict__ Kp,
                          float* __restrict__ VTf, float* __restrict__ VTl){
  int gid = blockIdx.x*256+threadIdx.x;
  if(gid < 196608){
    int j = gid / 384;
    Kp[gid] = (j<500) ? K1[gid] : 0.f;
    return;
  }
  int g2 = gid - 196608;
  const float* V; float* VT;
  if(g2 < 196608){ V = Vf; VT = VTf; }
  else { g2 -= 196608; if(g2 >= 196608) return; V = Vl; VT = VTl; }
  int j = g2 & 511; int d = (g2>>9) & 63; int h = g2 >> 15;
  VT[g2] = (j<500) ? V[(size_t)j*384 + h*64 + d] : 0.f;
}

__global__ void compose_bias(const float* __restrict__ inw, const float* __restrict__ inb,
                             const float* __restrict__ qb, const float* __restrict__ kb,
                             const float* __restrict__ vb, float* __restrict__ cb){
  int gid = blockIdx.x*256+threadIdx.x;
  if(gid>=1536) return;
  int seg = gid/384, i = gid%384;
  const float* wrow; const float* bsrc; float b2;
  if(seg==0){ wrow=inw + (size_t)i*384;       bsrc=qb; b2=inb[i]; }
  else if(seg==1){ wrow=inw + (size_t)(384+i)*384; bsrc=kb; b2=inb[384+i]; }
  else if(seg==2){ wrow=inw + (size_t)(768+i)*384; bsrc=vb; b2=inb[768+i]; }
  else          { wrow=inw + (size_t)(768+i)*384; bsrc=kb; b2=inb[768+i]; }
  float s=0.f;
  for(int t=0;t<384;t++) s = fmaf(wrow[t], bsrc[t], s);
  cb[gid] = s + b2;
}

#define NSEG 18
struct SplitArgs {
  const float* src[NSEG];
  unsigned short* dh[NSEG];
  unsigned short* dl[NSEG];
  int start[NSEG+1];
  int ld[NSEG];
};
// split f32 -> bf16 hi/lo, writing into tile-blocked LDS-image (XOR-swizzled) layout
__global__ void split_all(SplitArgs a){
  int gid = blockIdx.x*256+threadIdx.x;
  if(gid >= a.start[NSEG]) return;
  int s=0;
  while(s<NSEG-1 && gid >= a.start[s+1]) s++;
  int off = gid - a.start[s];
  int K = a.ld[s];
  int r = off / K, c = off - r*K;
  int dst = ((r>>6)*(K>>6) + (c>>6))*4096 + ((r&63)<<6) + ((c&63) ^ ((r&7)<<3));
  float v = a.src[s][off];
  unsigned short h = f2bf(v);
  a.dh[s][dst] = h;
  a.dl[s][dst] = f2bf(v - bf2f(h));
}

__global__ void seq_init(const int* __restrict__ inp, const float* __restrict__ emb,
                         const float* __restrict__ rp, float* __restrict__ seq){
  int gid = blockIdx.x*256+threadIdx.x;
  if(gid >= 128*8*384) return;
  int j = gid % 384; int l = (gid/384) & 7; int b = gid / 3072;
  int tok = inp[b*8 + l];
  seq[gid] = emb[(size_t)tok*384 + j] + rp[l*384 + j];
}

// ---------------- merge-loop kernels ----------------
__global__ void build_pairs(const float* __restrict__ seq, const float* __restrict__ rp,
                            float* __restrict__ pairs, int N, int P){
  int gid = blockIdx.x*256+threadIdx.x;
  if(gid >= N*768) return;
  int c = gid % 768; int n = gid / 768;
  int t = c / 384; int j = c % 384;
  int i = n % P; int b = n / P;
  pairs[gid] = seq[((size_t)b*8 + i + t)*384 + j] + rp[t*384 + j];
}

// fused len-2 attention: one block per pair (scores + softmax + PV)
__global__ __launch_bounds__(256)
void attn2_one(const float* __restrict__ QKV, float* __restrict__ O, int N){
  int n = blockIdx.x;
  if(n>=N) return;
  int tid = threadIdx.x, lane = tid&63, h = tid>>6;
  __shared__ float pr[4][2][2];
  const float* base = QKV + (size_t)(2*n)*1152;
  const float* q0 = base + h*96;
  const float* q1 = base + 1152 + h*96;
  const float* k0 = base + 384 + h*96;
  const float* k1 = base + 1152 + 384 + h*96;
  float q0a=q0[lane], q1a=q1[lane], k0a=k0[lane], k1a=k1[lane];
  float q0b=0.f,q1b=0.f,k0b=0.f,k1b=0.f;
  if(lane<32){ q0b=q0[64+lane]; q1b=q1[64+lane]; k0b=k0[64+lane]; k1b=k1[64+lane]; }
  float s00 = waveSum(q0a*k0a + q0b*k0b);
  float s01 = waveSum(q0a*k1a + q0b*k1b);
  float s10 = waveSum(q1a*k0a + q1b*k0b);
  float s11 = waveSum(q1a*k1a + q1b*k1b);
  if(lane==0){
    const float sc = 0.1020620726159658f;   // 1/sqrt(96)
    s00*=sc; s01*=sc; s10*=sc; s11*=sc;
    float m0=fmaxf(s00,s01); float e00=expf(s00-m0), e01=expf(s01-m0); float i0=1.f/(e00+e01);
    float m1=fmaxf(s10,s11); float e10=expf(s10-m1), e11=expf(s11-m1); float i1=1.f/(e10+e11);
    pr[h][0][0]=e00*i0; pr[h][0][1]=e01*i0;
    pr[h][1][0]=e10*i1; pr[h][1][1]=e11*i1;
  }
  __syncthreads();
  const float* v0 = base + 768;
  const float* v1 = base + 1152 + 768;
  float* o = O + (size_t)(2*n)*384;
#pragma unroll
  for(int i=0;i<3;i++){
    int c = tid + i*256;
    int t = c / 384, j = c % 384; int hh = j/96;
    o[(size_t)t*384 + j] = pr[hh][t][0]*v0[j] + pr[hh][t][1]*v1[j];
  }
}

// fused optional-scatter + score + argmax + entropy + gather from hid[b][7][384]
__global__ __launch_bounds__(256)
void score_select3(float* __restrict__ hid, const float* __restrict__ xb,
                   const float* __restrict__ w, const float* __restrict__ b0,
                   int P, int* __restrict__ idxb, float* __restrict__ lossSlot,
                   float* __restrict__ sel, int doScatter){
  int b = blockIdx.x;
  int tid = threadIdx.x, lane = tid&63, wv = tid>>6;
  __shared__ float scs[8];
  __shared__ int sidx;
  if(doScatter){
    int oldIdx = idxb[b];
#pragma unroll
    for(int e=0;e<2;e++){
      int s = oldIdx-1+e; s = max(0, min(s, P-1));
      const float* src = xb + ((size_t)(2*(2*b+e)+1))*384;
      float* dst = hid + ((size_t)b*7 + s)*384;
      for(int c=tid;c<384;c+=256) dst[c] = src[c];
      __syncthreads();
    }
  }
  for(int pi=wv; pi<P; pi+=4){
    const float* x = hid + ((size_t)b*7 + pi)*384;
    float s=0.f;
#pragma unroll
    for(int i=0;i<6;i++){ int c = lane + i*64; s = fmaf(x[c], w[c], s); }
    s = waveSum(s);
    if(lane==0) scs[pi] = 1.f/(1.f+expf(-(s + b0[0])));
  }
  __syncthreads();
  if(tid==0){
    float m = scs[0]; int am = 0;
    for(int i=1;i<P;i++){ float v=scs[i]; if(v>m){m=v;am=i;} }
    float z=0.f, sx=0.f;
    for(int i=0;i<P;i++){ float e=expf(scs[i]-m); z+=e; sx=fmaf(e,scs[i],sx); }
    lossSlot[(size_t)b*9] = (m + logf(z)) - sx/z;
    idxb[b] = am;
    sidx = am;
  }
  __syncthreads();
  const float* src = hid + ((size_t)b*7 + sidx)*384;
  for(int c=tid;c<384;c+=256) sel[(size_t)b*384+c] = src[c];
}

// ---------------- attention epilogue kernels ----------------
// softmax over 500 GEMM scores + NE extra keys computed in-kernel
template<int NE>
__global__ __launch_bounds__(256)
void softmax_ext2(float* __restrict__ S, const float* __restrict__ qkv1,
                  float* __restrict__ E, int R){
  int m = blockIdx.x;
  int r = m % R, h = m / R;
  int rbase = (NE==2) ? (r & ~1) : r;
  float* x = S + (size_t)m*512;
  int tid = threadIdx.x, lane = tid&63, wv = tid>>6;
  __shared__ float r4[4];
  __shared__ float exs[2];
  if(wv < NE){
    const float* q = qkv1 + (size_t)r*1152 + h*64;
    const float* k = qkv1 + (size_t)(rbase+wv)*1152 + 384 + h*64;
    float s = waveSum(q[lane]*k[lane]) * 0.125f;
    if(lane==0) exs[wv] = s;
  }
  __syncthreads();
  float mx = -1e30f;
  for(int c=tid;c<500;c+=256) mx = fmaxf(mx, x[c]);
  if(tid < NE) mx = fmaxf(mx, exs[tid]);
  mx = waveMax(mx);
  if(lane==0) r4[wv]=mx;
  __syncthreads();
  mx = fmaxf(fmaxf(r4[0],r4[1]),fmaxf(r4[2],r4[3]));
  float s=0.f;
  for(int c=tid;c<500;c+=256){ float e=expf(x[c]-mx); x[c]=e; s+=e; }
  float et=0.f;
  if(tid < NE){ et=expf(exs[tid]-mx); s+=et; }
  s = waveSum(s);
  __syncthreads();
  if(lane==0) r4[wv]=s;
  __syncthreads();
  float inv = 1.f/(r4[0]+r4[1]+r4[2]+r4[3]);
  for(int c=tid;c<500;c+=256) x[c]*=inv;
  if(tid < NE) E[(size_t)m*NE+tid] = et*inv;
}

// PV epilogue: sum KS=8 split-K partials + extra-key contributions
template<int NE>
__global__ void pv_epi2(const float* __restrict__ Pp, const float* __restrict__ E,
                        const float* __restrict__ qkv, float* __restrict__ O, int R){
  int gid = blockIdx.x*256+threadIdx.x;
  if(gid >= R*384) return;
  int r = gid / 384; int c = gid % 384; int h = c >> 6; int d = c & 63;
  int m = h*R + r;
  int rbase = (NE==2) ? (r & ~1) : r;
  const float* p = Pp + ((size_t)(h*8)*R + r)*64 + d;
  float v = 0.f;
#pragma unroll
  for(int k=0;k<8;k++) v += p[(size_t)k*R*64];
#pragma unroll
  for(int e=0;e<NE;e++)
    v = fmaf(E[(size_t)m*NE+e], qkv[(size_t)(rbase+e)*1152 + 768 + c], v);
  O[gid] = v;
}

// merge_seq + merge_hid + build pairs for NEXT iteration, one kernel
__global__ void merge_all(const float* __restrict__ seqOld, const float* __restrict__ fused,
                          const float* __restrict__ hidOld, const float* __restrict__ rp,
                          const int* __restrict__ idxb,
                          float* __restrict__ seqNew, float* __restrict__ hidNew,
                          float* __restrict__ pairs, int P, int last){
  int gid = blockIdx.x*256+threadIdx.x;
  int nA = 128*P*384;
  if(gid < nA){
    int j = gid % 384; int rest = gid / 384; int i = rest % P; int b = rest / P;
    int id = idxb[b];
    float v = (i==id) ? fused[(size_t)b*384+j]
                      : seqOld[((size_t)b*8 + i + (i>id?1:0))*384 + j];
    seqNew[((size_t)b*8+i)*384+j] = v;
    return;
  }
  if(last) return;
  gid -= nA;
  int Pn = P-1;
  int nB = 128*Pn*384;
  if(gid < nB){
    int j = gid % 384; int rest = gid / 384; int i = rest % Pn; int b = rest / Pn;
    int idx = idxb[b];
    int si = i + (i>=idx ? 1 : 0);
    hidNew[((size_t)b*7+i)*384+j] = hidOld[((size_t)b*7+si)*384+j];
    return;
  }
  gid -= nB;
  if(gid >= 256*768) return;
  int c = gid % 768; int rr = gid / 768; int b = rr>>1; int e = rr&1;
  int idx = idxb[b];
  int s = idx-1+e; s = max(0, min(s, Pn-1));
  int t = c/384, j = c%384;
  int row = s+t;   // row in NEW sequence
  float v = (row==idx) ? fused[(size_t)b*384+j]
                       : seqOld[((size_t)b*8 + row + (row>idx?1:0))*384 + j];
  pairs[gid] = v + rp[t*384+j];
}

__global__ void compact_seq(const float* __restrict__ seq, float* __restrict__ out,
                            float* __restrict__ lossBase){
  int gid = blockIdx.x*256+threadIdx.x;
  if(gid < 128) lossBase[(size_t)gid*9 + 6] = 0.f;
  if(gid >= 256*384) return;
  int j = gid % 384; int r = gid / 384; int b = r>>1; int t = r&1;
  out[gid] = seq[((size_t)b*8 + t)*384 + j];
}

__global__ void logits_k(const float* __restrict__ x2, const float* __restrict__ relmem,
                         const float* __restrict__ seqf, float* __restrict__ out){
  int gid = blockIdx.x*256+threadIdx.x;
  if(gid >= 256*502) return;
  int m = gid % 502; int bt = gid / 502; int b = bt>>1;
  const float* x = x2 + (size_t)bt*384;
  const float* mr = (m<500) ? relmem + (size_t)m*384 : seqf + ((size_t)b*2 + (m-500))*384;
  float s=0.f;
#pragma unroll 8
  for(int d=0;d<384;d++) s = fmaf(x[d], mr[d], s);
  out[gid] = s * 0.05103103630798288f;
}

__global__ void pred_copy(const float* __restrict__ logits, float* __restrict__ out){
  int gid = blockIdx.x*256+threadIdx.x;
  if(gid >= 128*502) return;
  int m = gid % 502; int b = gid / 502;
  out[gid] = logits[((size_t)b*2+1)*502 + m];
}

__global__ __launch_bounds__(256)
void final_ent(const float* __restrict__ L2, float* __restrict__ lossBase){
  int row = blockIdx.x;
  const float* x = L2 + (size_t)row*502;
  int tid = threadIdx.x;
  float m = -1e30f;
  for(int c=tid;c<502;c+=256) m = fmaxf(m, x[c]);
  m = waveMax(m);
  __shared__ float sm[4];
  if((tid&63)==0) sm[tid>>6]=m;
  __syncthreads();
  m = fmaxf(fmaxf(sm[0],sm[1]),fmaxf(sm[2],sm[3]));
  float s=0.f, sx=0.f;
  for(int c=tid;c<502;c+=256){ float e=expf(x[c]-m); s+=e; sx=fmaf(e,x[c],sx); }
  s = waveSum(s); sx = waveSum(sx);
  __shared__ float ps[4], px[4];
  if((tid&63)==0){ ps[tid>>6]=s; px[tid>>6]=sx; }
  __syncthreads();
  if(tid==0){
    float S = ps[0]+ps[1]+ps[2]+ps[3];
    float SX = px[0]+px[1]+px[2]+px[3];
    float ent = (m + logf(S)) - SX/S;
    int b = row>>1, t = row&1;
    lossBase[(size_t)b*9 + 7 + t] = ent;
  }
}

// ---------------- host ----------------
extern "C" void kernel_launch(void* const* d_in, const int* in_sizes, int n_in,
                              void* d_out, int out_size, void* d_ws, size_t ws_size,
                              hipStream_t stream){
  (void)in_sizes; (void)n_in; (void)out_size; (void)ws_size;
  const int*   inputs    = (const int*)  d_in[0];
  const float* emb       = (const float*)d_in[1];
  const float* rel_pos   = (const float*)d_in[2];
  const float* qkv_dyn_w = (const float*)d_in[3];
  const float* qkv_dyn_b = (const float*)d_in[4];
  const float* out_dyn_w = (const float*)d_in[5];
  const float* out_dyn_b = (const float*)d_in[6];
  const float* ln_dyn_g  = (const float*)d_in[7];
  const float* ln_dyn_b  = (const float*)d_in[8];
  const float* conv_w    = (const float*)d_in[9];
  const float* conv_b    = (const float*)d_in[10];
  const float* tl_in_w   = (const float*)d_in[11];
  const float* tl_in_b   = (const float*)d_in[12];
  const float* tl_out_w  = (const float*)d_in[13];
  const float* tl_out_b  = (const float*)d_in[14];
  const float* tl_ln1_g  = (const float*)d_in[15];
  const float* tl_ln1_b  = (const float*)d_in[16];
  const float* tl_ln2_g  = (const float*)d_in[17];
  const float* tl_ln2_b  = (const float*)d_in[18];
  const float* tl_ff1_w  = (const float*)d_in[19];
  const float* tl_ff1_b  = (const float*)d_in[20];
  const float* tl_ff2_w  = (const float*)d_in[21];
  const float* tl_ff2_b  = (const float*)d_in[22];
  const float* fc_score_w= (const float*)d_in[23];
  const float* fc_score_b= (const float*)d_in[24];
  const float* fcq_w     = (const float*)d_in[25];
  const float* fcq_b     = (const float*)d_in[26];
  const float* fck_w     = (const float*)d_in[27];
  const float* fck_b     = (const float*)d_in[28];
  const float* fcv_w     = (const float*)d_in[29];
  const float* fcv_b     = (const float*)d_in[30];
  const float* mha_in_w  = (const float*)d_in[31];
  const float* mha_in_b  = (const float*)d_in[32];
  const float* mha_out_w = (const float*)d_in[33];
  const float* mha_out_b = (const float*)d_in[34];
  const float* lnf1_g    = (const float*)d_in[35];
  const float* lnf1_b    = (const float*)d_in[36];
  const float* lnf2_g    = (const float*)d_in[37];
  const float* lnf2_b    = (const float*)d_in[38];
  const float* ff1_w     = (const float*)d_in[39];
  const float* ff1_b     = (const float*)d_in[40];
  const float* ff2_w     = (const float*)d_in[41];
  const float* ff2_b     = (const float*)d_in[42];

  float* ws = (float*)d_ws;
  size_t off = 0;
  auto Aa = [&](size_t n){ float* p = ws + off; off += n; return p; };
  float* relmem = Aa(192000);
  float* K1mem  = Aa(192000);
  float* V1f    = Aa(192000);
  float* V1l    = Aa(192000);
  float* K1padf = Aa(196608);   // [512][384]
  float* VT1f   = Aa(196608);   // [6][64][512]
  float* VT1lf  = Aa(196608);   // [6][64][512]
  float* cb     = Aa(1536);
  float* cb768  = Aa(768);
  float* seqA_  = Aa(393216);
  float* seqB_  = Aa(393216);
  float* hidA_  = Aa(344064);   // [128][7][384]
  float* hidB_  = Aa(344064);
  float* fqkv1  = Aa(147456);
  float* gqkv1  = Aa(294912);
  unsigned short* SH = (unsigned short*)Aa(3514368);
  unsigned short* SL = (unsigned short*)Aa(3514368);
  float* Pp     = Aa(2359296);  // split-K partials
  float* pairs  = Aa(688128);
  float* xbuf   = Aa(688128);
  float* qkvbuf = Aa(2064384);
  float* obuf   = Aa(688128);
  float* tmpb   = Aa(688128);
  float* ffbuf  = Aa(2752512);
  float* probs2 = Aa(14336);
  int*   idxb   = (int*)Aa(128);
  float* sel    = Aa(49152);
  float* fo     = Aa(49152);
  float* fxf    = Aa(49152);
  float* ffused = Aa(49152);
  float* fffb   = Aa(196608);

  // setup-phase temps inside ffbuf
  float* sc512   = ffbuf;                // 2*500*512 = 512000
  float* Cfuse3f = ffbuf + 600000;       // 1152*384 = 442368
  float* Cvkf    = ffbuf + 1100000;      // 147456
  float* Wconvf  = ffbuf + 1300000;      // 589824
  float* VT      = tmpb;                 // 2*192*512 = 196608
  // attention temps (alias dead arenas during attention phases)
  float* Sbuf = ffbuf;                   // up to 6*256*512 = 786432
  float* Ebuf = probs2;                  // up to 6*256*2   = 3072
  // final-stage aliases
  float* seqf = pairs;
  float* go   = obuf;
  float* gx1  = obuf + 196608;
  float* gx2  = obuf + 294912;
  float* logitsb = qkvbuf;

  float* lossBase = (float*)d_out + 128*502;

  // split-arena segment offsets (ushort elements)
  const int o_qkvdyn=0, o_outdyn=442368, o_wconv=589824,
            o_tlin0=1179648, o_tlin1=1622016, o_tlout0=2064384, o_tlout1=2211840,
            o_tlff1_0=2359296, o_tlff1_1=2949120, o_tlff2_0=3538944, o_tlff2_1=4128768,
            o_mhaout=4718592, o_ff1=4866048, o_ff2=5455872, o_cfuse=6045696, o_cvk=6488064,
            o_vtf=6635520, o_vtl=6832128;
  const int split_total = 7028736;

  const float s192 = 0.07216878364870322f;  // 1/sqrt(192)

  // ---------- stage 1: relation_mem ----------
  gemm3<0><<<dim3(8,18),256,0,stream>>>(emb,384, qkv_dyn_w,384, qkvbuf,1152, qkv_dyn_b, 500,1152,384, 1.f);
  for(int h=0;h<2;h++)
    gemm3<0><<<dim3(8,8),256,0,stream>>>(qkvbuf + h*192,1152, qkvbuf + 384 + h*192,1152,
           sc512 + (size_t)h*256000,512, nullptr, 500,512,192, s192);
  softmax_rows<<<1000,256,0,stream>>>(sc512, 512, 500);
  vt_k<<<CDIV(2*192*512,256),256,0,stream>>>(qkvbuf, VT);
  for(int h=0;h<2;h++)
    gemm3<0><<<dim3(8,3),256,0,stream>>>(sc512 + (size_t)h*256000,512, VT + h*98304,512,
           obuf + h*192,384, nullptr, 500,192,512, 1.f);
  gemm3<0><<<dim3(8,6),256,0,stream>>>(obuf,384, out_dyn_w,384, xbuf,384, out_dyn_b, 500,384,384, 1.f);
  add_ln<<<500,128,0,stream>>>(emb, xbuf, relmem, ln_dyn_g, ln_dyn_b, 500, nullptr);

  // ---------- compositions ----------
  gemm_nn<<<dim3(6,6),256,0,stream>>>(mha_in_w,384,            fcq_w,384, Cfuse3f,384,          384,384,384, 1.f);
  gemm_nn<<<dim3(6,6),256,0,stream>>>(mha_in_w + 384*384,384,  fck_w,384, Cfuse3f + 147456,384, 384,384,384, 1.f);
  gemm_nn<<<dim3(6,6),256,0,stream>>>(mha_in_w + 768*384,384,  fcv_w,384, Cfuse3f + 294912,384, 384,384,384, 1.f);
  gemm_nn<<<dim3(6,6),256,0,stream>>>(mha_in_w + 768*384,384,  fck_w,384, Cvkf,384,             384,384,384, 1.f);
  compose_bias<<<6,256,0,stream>>>(mha_in_w, mha_in_b, fcq_b, fck_b, fcv_b, cb);

  // ---------- batch-invariant K/V for fuse/final ----------
  gemm3<0><<<dim3(8,6),256,0,stream>>>(relmem,384, Cfuse3f + 147456,384, K1mem,384, cb+384,  500,384,384, 1.f);
  gemm3<0><<<dim3(8,6),256,0,stream>>>(relmem,384, Cfuse3f + 294912,384, V1f,384,   cb+768,  500,384,384, 1.f);
  gemm3<0><<<dim3(8,6),256,0,stream>>>(relmem,384, Cvkf,384,            V1l,384,   cb+1152, 500,384,384, 1.f);
  prep_attn<<<CDIV(3*196608,256),256,0,stream>>>(K1mem, V1f, V1l, K1padf, VT1f, VT1lf);

  prep_conv<<<CDIV(384*384,256),256,0,stream>>>(conv_w, conv_b, Wconvf, cb768);

  // ---------- split all hot-loop weights into tile-swizzled hi/lo ----------
  {
    SplitArgs a;
    const float* srcs[NSEG] = { qkv_dyn_w, out_dyn_w, Wconvf, tl_in_w, tl_in_w + 442368,
                                tl_out_w, tl_out_w + 147456, tl_ff1_w, tl_ff1_w + 589824,
                                tl_ff2_w, tl_ff2_w + 589824, mha_out_w, ff1_w, ff2_w,
                                Cfuse3f, Cvkf, VT1f, VT1lf };
    const int offs[NSEG+1] = { o_qkvdyn, o_outdyn, o_wconv, o_tlin0, o_tlin1, o_tlout0, o_tlout1,
                               o_tlff1_0, o_tlff1_1, o_tlff2_0, o_tlff2_1, o_mhaout, o_ff1, o_ff2,
                               o_cfuse, o_cvk, o_vtf, o_vtl, split_total };
    const int lds[NSEG] = { 384, 384, 768, 384, 384, 384, 384, 384, 384,
                            1536, 1536, 384, 384, 1536, 384, 384, 512, 512 };
    for(int s=0;s<NSEG;s++){
      a.src[s]=srcs[s]; a.dh[s]=SH+offs[s]; a.dl[s]=SL+offs[s]; a.start[s]=offs[s];
      a.ld[s]=lds[s];
    }
    a.start[NSEG]=split_total;
    split_all<<<CDIV(split_total,256),256,0,stream>>>(a);
  }
  seq_init<<<CDIV(128*8*384,256),256,0,stream>>>(inputs, emb, rel_pos, seqA_);

  float* seqCur = seqA_; float* seqNxt = seqB_;
  float* hidCur = hidA_; float* hidNxt = hidB_;

  // ---------- merge loop ----------
  for(int it=0; it<6; ++it){
    int P = 7 - it;
    if(it == 0){
      int N = 128*7, R2 = 2*N;   // 896 pairs, 1792 rows
      build_pairs<<<CDIV(N*768,256),256,0,stream>>>(seqCur, rel_pos, pairs, N, 7);
      gemm3s<0><<<dim3(N/64,12),256,0,stream>>>(pairs,768, SH+o_wconv,SL+o_wconv,768,
                                                xbuf,768, cb768, N,768,768);
      for(int l=0;l<2;l++){
        int oin  = l? o_tlin1  : o_tlin0;
        int oout = l? o_tlout1 : o_tlout0;
        int of1  = l? o_tlff1_1: o_tlff1_0;
        int of2  = l? o_tlff2_1: o_tlff2_0;
        gemm3s<0><<<dim3(R2/64,18),256,0,stream>>>(xbuf,384, SH+oin,SL+oin,384,
                                                   qkvbuf,1152, tl_in_b + l*1152, R2,1152,384);
        attn2_one<<<N,256,0,stream>>>(qkvbuf, obuf, N);
        gemm3s<0><<<dim3(R2/64,6),256,0,stream>>>(obuf,384, SH+oout,SL+oout,384,
                                                  tmpb,384, tl_out_b + l*384, R2,384,384);
        add_ln<<<R2,128,0,stream>>>(xbuf, tmpb, xbuf, tl_ln1_g + l*384, tl_ln1_b + l*384, R2, nullptr);
        gemm3s<1><<<dim3(R2/64,24),256,0,stream>>>(xbuf,384, SH+of1,SL+of1,384,
                                                   ffbuf,1536, tl_ff1_b + l*1536, R2,1536,384);
        gemm3s<0><<<dim3(R2/64,6),256,0,stream>>>(ffbuf,1536, SH+of2,SL+of2,1536,
                                                  tmpb,384, tl_ff2_b + l*384, R2,384,1536);
        add_ln<<<R2,128,0,stream>>>(xbuf, tmpb, xbuf, tl_ln2_g + l*384, tl_ln2_b + l*384, R2,
                                    (l==1) ? hidCur : nullptr);
      }
    } else {
      // incremental: pairs were built by previous iteration's merge_all
      const int N2 = 256, R2 = 512;
      gemm3bk<<<dim3(4,12,12),256,0,stream>>>(pairs,768,0, SH+o_wconv,SL+o_wconv,768,0,
                                              Pp, N2,768,64,12);
      reduce_k<0><<<CDIV(N2*768,256),256,0,stream>>>(Pp, xbuf, cb768, N2*768,768,768,0,12,1, 1.f);
      for(int l=0;l<2;l++){
        int oin  = l? o_tlin1  : o_tlin0;
        int oout = l? o_tlout1 : o_tlout0;
        int of1  = l? o_tlff1_1: o_tlff1_0;
        int of2  = l? o_tlff2_1: o_tlff2_0;
        gemm3s<0><<<dim3(R2/64,18),256,0,stream>>>(xbuf,384, SH+oin,SL+oin,384,
                                                   qkvbuf,1152, tl_in_b + l*1152, R2,1152,384);
        attn2_one<<<N2,256,0,stream>>>(qkvbuf, obuf, N2);
        gemm3bk<<<dim3(R2/64,6,6),256,0,stream>>>(obuf,384,0, SH+oout,SL+oout,384,0,
                                                  Pp, R2,384,64,6);
        reduce_ln<<<R2,128,0,stream>>>(Pp, xbuf, xbuf, tl_ln1_g + l*384, tl_ln1_b + l*384,
                                       tl_out_b + l*384, R2, 6);
        gemm3s<1><<<dim3(R2/64,24),256,0,stream>>>(xbuf,384, SH+of1,SL+of1,384,
                                                   ffbuf,1536, tl_ff1_b + l*1536, R2,1536,384);
        gemm3bk<<<dim3(R2/64,6,8),256,0,stream>>>(ffbuf,1536,0, SH+of2,SL+of2,1536,0,
                                                  Pp, R2,384,192,8);
        reduce_ln<<<R2,128,0,stream>>>(Pp, xbuf, xbuf, tl_ln2_g + l*384, tl_ln2_b + l*384,
                                       tl_ff2_b + l*384, R2, 8);
      }
    }
    score_select3<<<128,256,0,stream>>>(hidCur, xbuf, fc_score_w, fc_score_b, P, idxb,
                                        lossBase + it, sel, (it>0) ? 1 : 0);
    // fuse qkv: split-K
    gemm3bk<<<dim3(2,18,6),256,0,stream>>>(sel,384,0, SH+o_cfuse,SL+o_cfuse,384,0,
                                           Pp, 128,1152,64,6);
    reduce_k<0><<<CDIV(128*1152,256),256,0,stream>>>(Pp, fqkv1, cb, 128*1152,1152,1152,0,6,1, 1.f);
    // attention
    gemm3z<<<dim3(2,8,6),256,0,stream>>>(fqkv1,1152,64, K1padf,384,64,
                                         Sbuf,512,128*512, 128,512,64, 0.125f);
    softmax_ext2<1><<<768,256,0,stream>>>(Sbuf, fqkv1, Ebuf, 128);
    gemm3bk<<<dim3(2,1,48),256,0,stream>>>(Sbuf,512,65536, SH+o_vtf,SL+o_vtf,512,32768,
                                           Pp, 128,64,64,8);
    pv_epi2<1><<<CDIV(128*384,256),256,0,stream>>>(Pp, Ebuf, fqkv1, fo, 128);
    // mha_out: split-K + fused residual-LN
    gemm3bk<<<dim3(2,6,6),256,0,stream>>>(fo,384,0, SH+o_mhaout,SL+o_mhaout,384,0,
                                          Pp, 128,384,64,6);
    reduce_ln<<<128,128,0,stream>>>(Pp, sel, fxf, lnf1_g, lnf1_b, mha_out_b, 128, 6);
    // ff1: split-K + GELU
    gemm3bk<<<dim3(2,24,6),256,0,stream>>>(fxf,384,0, SH+o_ff1,SL+o_ff1,384,0,
                                           Pp, 128,1536,64,6);
    reduce_k<1><<<CDIV(128*1536,256),256,0,stream>>>(Pp, fffb, ff1_b, 128*1536,1536,1536,0,6,1, 1.f);
    // ff2: split-K + fused residual-LN
    gemm3bk<<<dim3(2,6,24),256,0,stream>>>(fffb,1536,0, SH+o_ff2,SL+o_ff2,1536,0,
                                           Pp, 128,384,64,24);
    reduce_ln<<<128,128,0,stream>>>(Pp, fxf, ffused, lnf2_g, lnf2_b, ff2_b, 128, 24);
    // merged seq/hid update + next-iteration pair build
    {
      int last = (it==5) ? 1 : 0;
      int total = 128*P*384 + (last ? 0 : (128*(P-1)*384 + 256*768));
      merge_all<<<CDIV(total,256),256,0,stream>>>(seqCur, ffused, hidCur, rel_pos, idxb,
                                                  seqNxt, hidNxt, pairs, P, last);
    }
    float* t1 = seqCur; seqCur = seqNxt; seqNxt = t1;
    float* t2 = hidCur; hidCur = hidNxt; hidNxt = t2;
  }

  // ---------- final stage (Lf = 2) ----------
  compact_seq<<<CDIV(256*384,256),256,0,stream>>>(seqCur, seqf, lossBase);
  gemm3bk<<<dim3(4,12,6),256,0,stream>>>(seqf,384,0, SH+o_cfuse,SL+o_cfuse,384,0,
                                         Pp, 256,768,64,6);
  reduce_k<0><<<CDIV(256*768,256),256,0,stream>>>(Pp, gqkv1, cb, 256*768,768,1152,0,6,1, 1.f);
  gemm3bk<<<dim3(4,6,6),256,0,stream>>>(seqf,384,0, SH+o_cvk,SL+o_cvk,384,0,
                                        Pp, 256,384,64,6);
  reduce_k<0><<<CDIV(256*384,256),256,0,stream>>>(Pp, gqkv1+768, cb+1152, 256*384,384,1152,0,6,1, 1.f);
  gemm3z<<<dim3(4,8,6),256,0,stream>>>(gqkv1,1152,64, K1padf,384,64,
                                       Sbuf,512,256*512, 256,512,64, 0.125f);
  softmax_ext2<2><<<1536,256,0,stream>>>(Sbuf, gqkv1, Ebuf, 256);
  gemm3bk<<<dim3(4,1,48),256,0,stream>>>(Sbuf,512,131072, SH+o_vtl,SL+o_vtl,512,32768,
                                         Pp, 256,64,64,8);
  pv_epi2<2><<<CDIV(256*384,256),256,0,stream>>>(Pp, Ebuf, gqkv1, go, 256);
  gemm3bk<<<dim3(4,6,6),256,0,stream>>>(go,384,0, SH+o_mhaout,SL+o_mhaout,384,0,
                                        Pp, 256,384,64,6);
  reduce_ln<<<256,128,0,stream>>>(Pp, seqf, gx1, lnf1_g, lnf1_b, mha_out_b, 256, 6);
  gemm3bk<<<dim3(4,24,6),256,0,stream>>>(gx1,384,0, SH+o_ff1,SL+o_ff1,384,0,
                                         Pp, 256,1536,64,6);
  reduce_k<1><<<CDIV(256*1536,256),256,0,stream>>>(Pp, ffbuf, ff1_b, 256*1536,1536,1536,0,6,1, 1.f);
  gemm3bk<<<dim3(4,6,24),256,0,stream>>>(ffbuf,1536,0, SH+o_ff2,SL+o_ff2,1536,0,
                                         Pp, 256,384,64,24);
  reduce_ln<<<256,128,0,stream>>>(Pp, gx1, gx2, lnf2_g, lnf2_b, ff2_b, 256, 24);
  logits_k<<<CDIV(256*502,256),256,0,stream>>>(gx2, relmem, seqf, logitsb);
  pred_copy<<<CDIV(128*502,256),256,0,stream>>>(logitsb, (float*)d_out);
  final_ent<<<256,256,0,stream>>>(logitsb, lossBase);
}